// Round 2
// baseline (9499.634 us; speedup 1.0000x reference)
//
#include <hip/hip_runtime.h>
#include <stdint.h>

#define NN 100000
#define NE 200000
#define NT 600000
// HID=256, HEADS=8, head_dim=32, layers=2
// initA padded K: 160 (147 real), finalA padded K: 416 (389 real)

__device__ __forceinline__ float bf2f(unsigned short u) {
    union { unsigned int i; float f; } x; x.i = ((unsigned int)u) << 16; return x.f;
}
__device__ __forceinline__ unsigned short f2bf(float f) {
    union { float f; unsigned int i; } x; x.f = f;
    unsigned int r = (x.i + 0x7FFFu + ((x.i >> 16) & 1u)) >> 16;
    return (unsigned short)r;
}

// ---------------------------------------------------------------------------
// fp32-accum GEMM: C[M][256] = post(A[M][K] @ B[Kreal][256])
// A dtype: bf16 (ABF) or f32. C dtype: bf16 (CBF) or f32.
// K = padded A row stride (multiple of 32, zero-filled beyond Kreal).
// FLAGS: 1 = relu, 2 = +bias (before relu), 4 = +res bf16 (after relu)
// BM=32, block=256 threads, thread tile 8 rows x 4 cols. M % 32 == 0.
// All LDS float4 accesses 16B-aligned (As stride 32 floats = 128B).
// ---------------------------------------------------------------------------
template<int FLAGS, bool ABF, bool CBF>
__global__ __launch_bounds__(256)
void gemm_n256(const void* __restrict__ Av, const float* __restrict__ B,
               const float* __restrict__ bias, const unsigned short* __restrict__ res,
               void* __restrict__ Cv, int M, int K, int Kreal)
{
    __shared__ float As[32][32];
    __shared__ float Bs[32][256];

    const int t    = threadIdx.x;
    const int row0 = blockIdx.x * 32;
    const int tx   = t & 63;        // cols tx*4 .. tx*4+3
    const int ty   = t >> 6;        // rows ty*8 .. ty*8+7

    float acc[8][4];
#pragma unroll
    for (int r = 0; r < 8; ++r)
#pragma unroll
        for (int c = 0; c < 4; ++c) acc[r][c] = 0.f;

    const int ar  = t >> 3;         // A stage row 0..31
    const int ak  = (t & 7) * 4;    // A stage k offset 0..28
    const int bc  = (t & 63) * 4;   // B stage col
    const int bk0 = (t >> 6) * 8;   // B stage k base

    for (int k0 = 0; k0 < K; k0 += 32) {
        // stage A tile (K multiple of 32: unguarded)
        {
            float4 af;
            if (ABF) {
                const unsigned short* A = (const unsigned short*)Av;
                const ushort4 raw = *reinterpret_cast<const ushort4*>(
                    A + (size_t)(row0 + ar) * K + k0 + ak);   // 8B-aligned by stride choice
                af.x = bf2f(raw.x); af.y = bf2f(raw.y);
                af.z = bf2f(raw.z); af.w = bf2f(raw.w);
            } else {
                const float* A = (const float*)Av;
                af = *reinterpret_cast<const float4*>(
                    A + (size_t)(row0 + ar) * K + k0 + ak);
            }
            *reinterpret_cast<float4*>(&As[ar][ak]) = af;
        }
        // stage B tile (guard ragged Kreal)
#pragma unroll
        for (int i = 0; i < 8; ++i) {
            const int kk = bk0 + i;
            float4 bv = make_float4(0.f, 0.f, 0.f, 0.f);
            if (k0 + kk < Kreal)
                bv = *reinterpret_cast<const float4*>(B + (size_t)(k0 + kk) * 256 + bc);
            *reinterpret_cast<float4*>(&Bs[kk][bc]) = bv;
        }
        __syncthreads();

#pragma unroll
        for (int kk = 0; kk < 32; kk += 4) {
            float4 a[8];
#pragma unroll
            for (int r = 0; r < 8; ++r)
                a[r] = *reinterpret_cast<const float4*>(&As[ty * 8 + r][kk]);
#pragma unroll
            for (int j = 0; j < 4; ++j) {
                const float4 b = *reinterpret_cast<const float4*>(&Bs[kk + j][tx * 4]);
#pragma unroll
                for (int r = 0; r < 8; ++r) {
                    const float av = (j == 0) ? a[r].x : (j == 1) ? a[r].y
                                   : (j == 2) ? a[r].z : a[r].w;
                    acc[r][0] += av * b.x;
                    acc[r][1] += av * b.y;
                    acc[r][2] += av * b.z;
                    acc[r][3] += av * b.w;
                }
            }
        }
        __syncthreads();
    }

    // epilogue
#pragma unroll
    for (int r = 0; r < 8; ++r) {
        const int row = row0 + ty * 8 + r;
        float4 o = make_float4(acc[r][0], acc[r][1], acc[r][2], acc[r][3]);
        if (FLAGS & 2) {
            const float4 bi = *reinterpret_cast<const float4*>(bias + tx * 4);
            o.x += bi.x; o.y += bi.y; o.z += bi.z; o.w += bi.w;
        }
        if (FLAGS & 1) {
            o.x = fmaxf(o.x, 0.f); o.y = fmaxf(o.y, 0.f);
            o.z = fmaxf(o.z, 0.f); o.w = fmaxf(o.w, 0.f);
        }
        if (FLAGS & 4) {
            const ushort4 rv = *reinterpret_cast<const ushort4*>(
                res + (size_t)row * 256 + tx * 4);
            o.x += bf2f(rv.x); o.y += bf2f(rv.y);
            o.z += bf2f(rv.z); o.w += bf2f(rv.w);
        }
        if (CBF) {
            unsigned short* C = (unsigned short*)Cv;
            ushort4 ov;
            ov.x = f2bf(o.x); ov.y = f2bf(o.y); ov.z = f2bf(o.z); ov.w = f2bf(o.w);
            *reinterpret_cast<ushort4*>(C + (size_t)row * 256 + tx * 4) = ov;
        } else {
            float* C = (float*)Cv;
            *reinterpret_cast<float4*>(C + (size_t)row * 256 + tx * 4) = o;
        }
    }
}

// ---------------------------------------------------------------------------
// initA[e][0:133]=atom[src[e]], [133:147]=edge[e], [147:160)=0   (bf16 out)
// ---------------------------------------------------------------------------
__global__ __launch_bounds__(256)
void build_initA(const float* __restrict__ atom, const float* __restrict__ edge,
                 const int* __restrict__ src, unsigned short* __restrict__ out)
{
    const long total = (long)NE * 160;
    long idx = (long)blockIdx.x * blockDim.x + threadIdx.x;
    if (idx >= total) return;
    const int e = (int)(idx / 160);
    const int c = (int)(idx - (long)e * 160);
    float v = 0.f;
    if (c < 133)      v = atom[(size_t)src[e] * 133 + c];
    else if (c < 147) v = edge[(size_t)e * 14 + (c - 133)];
    out[idx] = f2bf(v);
}

// ---------------------------------------------------------------------------
// finalA[n][0:133]=atom[n], [133:389]=fsum[n], [389:416)=0   (bf16 out)
// ---------------------------------------------------------------------------
__global__ __launch_bounds__(256)
void build_finalA(const float* __restrict__ atom, const float* __restrict__ fsum,
                  unsigned short* __restrict__ out)
{
    const long total = (long)NN * 416;
    long idx = (long)blockIdx.x * blockDim.x + threadIdx.x;
    if (idx >= total) return;
    const int n = (int)(idx / 416);
    const int c = (int)(idx - (long)n * 416);
    float v = 0.f;
    if (c < 133)      v = atom[(size_t)n * 133 + c];
    else if (c < 389) v = fsum[(size_t)n * 256 + (c - 133)];
    out[idx] = f2bf(v);
}

// ---------------------------------------------------------------------------
// Attention logits: one wave per triplet. lane covers dims lane*4..+3,
// head h = lane>>3 (8 lanes/head, d=32).
// att[t][h] = exp(leaky_relu(q[kj][h]·k[ji][h], 0.2)); denom[ji][h] += att.
// ---------------------------------------------------------------------------
__global__ __launch_bounds__(256)
void att_kernel(const unsigned short* __restrict__ q, const unsigned short* __restrict__ k,
                const int* __restrict__ idx_kj, const int* __restrict__ idx_ji,
                float* __restrict__ att, float* __restrict__ denom)
{
    const int w    = (int)(((long)blockIdx.x * blockDim.x + threadIdx.x) >> 6);
    const int lane = threadIdx.x & 63;
    if (w >= NT) return;
    const int kj = idx_kj[w];
    const int ji = idx_ji[w];
    const ushort4 qv = *reinterpret_cast<const ushort4*>(q + (size_t)kj * 256 + lane * 4);
    const ushort4 kv = *reinterpret_cast<const ushort4*>(k + (size_t)ji * 256 + lane * 4);
    float s = bf2f(qv.x) * bf2f(kv.x) + bf2f(qv.y) * bf2f(kv.y)
            + bf2f(qv.z) * bf2f(kv.z) + bf2f(qv.w) * bf2f(kv.w);
    s += __shfl_xor(s, 1);
    s += __shfl_xor(s, 2);
    s += __shfl_xor(s, 4);
    if ((lane & 7) == 0) {
        const float lr = (s > 0.f) ? s : 0.2f * s;
        const float a  = __expf(lr);
        const int h = lane >> 3;
        att[(size_t)w * 8 + h] = a;
        atomicAdd(&denom[(size_t)ji * 8 + h], a);
    }
}

// ---------------------------------------------------------------------------
// v_clone[ji] += v[kj] * (att[t][h]/denom[ji][h]); one wave per triplet.
// ---------------------------------------------------------------------------
__global__ __launch_bounds__(256)
void scatter_v(const unsigned short* __restrict__ v, const float* __restrict__ att,
               const float* __restrict__ denom,
               const int* __restrict__ idx_kj, const int* __restrict__ idx_ji,
               float* __restrict__ v_clone)
{
    const int w    = (int)(((long)blockIdx.x * blockDim.x + threadIdx.x) >> 6);
    const int lane = threadIdx.x & 63;
    if (w >= NT) return;
    const int kj = idx_kj[w];
    const int ji = idx_ji[w];
    const int h  = lane >> 3;
    const float wgt = att[(size_t)w * 8 + h] / denom[(size_t)ji * 8 + h];
    const ushort4 vv = *reinterpret_cast<const ushort4*>(v + (size_t)kj * 256 + lane * 4);
    float* out = v_clone + (size_t)ji * 256 + lane * 4;
    atomicAdd(out + 0, bf2f(vv.x) * wgt);
    atomicAdd(out + 1, bf2f(vv.y) * wgt);
    atomicAdd(out + 2, bf2f(vv.z) * wgt);
    atomicAdd(out + 3, bf2f(vv.w) * wgt);
}

// ---------------------------------------------------------------------------
// fsum[dst[e]] += feats[e]; one wave per edge.
// ---------------------------------------------------------------------------
__global__ __launch_bounds__(256)
void edge_to_node(const unsigned short* __restrict__ feats, const int* __restrict__ dst,
                  float* __restrict__ fsum)
{
    const int w    = (int)(((long)blockIdx.x * blockDim.x + threadIdx.x) >> 6);
    const int lane = threadIdx.x & 63;
    if (w >= NE) return;
    const int d = dst[w];
    const ushort4 f = *reinterpret_cast<const ushort4*>(feats + (size_t)w * 256 + lane * 4);
    float* out = fsum + (size_t)d * 256 + lane * 4;
    atomicAdd(out + 0, bf2f(f.x));
    atomicAdd(out + 1, bf2f(f.y));
    atomicAdd(out + 2, bf2f(f.z));
    atomicAdd(out + 3, bf2f(f.w));
}

// ---------------------------------------------------------------------------
extern "C" void kernel_launch(void* const* d_in, const int* in_sizes, int n_in,
                              void* d_out, int out_size, void* d_ws, size_t ws_size,
                              hipStream_t stream)
{
    const float* atom = (const float*)d_in[0];
    const float* edge = (const float*)d_in[1];
    const float* W_i  = (const float*)d_in[2];
    const float* Wq   = (const float*)d_in[3];
    const float* Wk   = (const float*)d_in[4];
    const float* Wv   = (const float*)d_in[5];
    const float* L1w  = (const float*)d_in[6];
    const float* L1b  = (const float*)d_in[7];
    const float* L2w  = (const float*)d_in[8];
    const float* L2b  = (const float*)d_in[9];
    const float* Wo   = (const float*)d_in[10];
    const float* bo   = (const float*)d_in[11];
    const int* src    = (const int*)d_in[12];
    const int* dst    = (const int*)d_in[13];
    const int* idx_kj = (const int*)d_in[14];
    const int* idx_ji = (const int*)d_in[15];

    // workspace layout (bytes):
    //   r0 [0, 102.4M)        feats bf16 [NE*256]; low half of v_clone f32
    //   r1 [102.4M, 204.8M)   q bf16 / initA bf16 / fsum f32; high half of v_clone
    //   r2 [204.8M, 307.2M)   k bf16 / h1 bf16 / finalA bf16
    //   att   [307.2M, 326.4M)  f32 [NT*8]
    //   denom [326.4M, 332.8M)  f32 [NE*8]
    // v bf16 lives in d_out (NN*256*4 B == NE*256*2 B exactly).
    const size_t RB = (size_t)NE * 256 * 2;           // 102,400,000 B
    const size_t NEEDED = 3 * RB + (size_t)NT * 8 * 4 + (size_t)NE * 8 * 4;
    if (ws_size < NEEDED) return;   // diagnostic: fail absmax instead of faulting

    char* ws = (char*)d_ws;
    unsigned short* feats  = (unsigned short*)(ws);
    unsigned short* qb     = (unsigned short*)(ws + RB);
    unsigned short* kb     = (unsigned short*)(ws + 2 * RB);
    float*          att    = (float*)(ws + 3 * RB);
    float*          denom  = (float*)(ws + 3 * RB + (size_t)NT * 8 * 4);
    unsigned short* vb     = (unsigned short*)d_out;
    float*          v_clone = (float*)(ws);           // r0+r1, f32 [NE*256]
    unsigned short* initA  = qb;
    unsigned short* h1     = kb;
    float*          fsum   = (float*)(ws + RB);       // r1, f32 [NN*256]
    unsigned short* finalA = kb;

    // ---- init: feats = relu(concat(atom[src], edge) @ W_i) ----
    {
        const long total = (long)NE * 160;
        build_initA<<<(int)((total + 255) / 256), 256, 0, stream>>>(atom, edge, src, initA);
    }
    gemm_n256<1, true, true><<<NE / 32, 256, 0, stream>>>(initA, W_i, nullptr, nullptr,
                                                          feats, NE, 160, 147);

    // ---- 2 attention layers ----
    for (int l = 0; l < 2; ++l) {
        const float* wq  = Wq  + (size_t)l * 256 * 256;
        const float* wk  = Wk  + (size_t)l * 256 * 256;
        const float* wv  = Wv  + (size_t)l * 256 * 256;
        const float* l1w = L1w + (size_t)l * 256 * 256;
        const float* l1b = L1b + (size_t)l * 256;
        const float* l2w = L2w + (size_t)l * 256 * 256;
        const float* l2b = L2b + (size_t)l * 256;

        gemm_n256<0, true, true><<<NE / 32, 256, 0, stream>>>(feats, wq, nullptr, nullptr, qb, NE, 256, 256);
        gemm_n256<0, true, true><<<NE / 32, 256, 0, stream>>>(feats, wk, nullptr, nullptr, kb, NE, 256, 256);
        gemm_n256<0, true, true><<<NE / 32, 256, 0, stream>>>(feats, wv, nullptr, nullptr, vb, NE, 256, 256);

        hipMemsetAsync(denom, 0, (size_t)NE * 8 * 4, stream);
        att_kernel<<<NT / 4, 256, 0, stream>>>(qb, kb, idx_kj, idx_ji, att, denom);

        // v_clone (f32) overlays feats+q regions; both dead by now
        hipMemsetAsync(v_clone, 0, (size_t)NE * 256 * 4, stream);
        scatter_v<<<NT / 4, 256, 0, stream>>>(vb, att, denom, idx_kj, idx_ji, v_clone);

        // h1 = relu(v_clone @ L1w + L1b)   (h1 -> k region, k dead)
        gemm_n256<3, false, true><<<NE / 32, 256, 0, stream>>>(v_clone, l1w, l1b, nullptr, h1, NE, 256, 256);
        // feats = v + relu(h1 @ L2w + L2b) (v_clone dead -> feats into r0)
        gemm_n256<7, true, true><<<NE / 32, 256, 0, stream>>>(h1, l2w, l2b, vb, feats, NE, 256, 256);
    }

    // ---- edge -> node sum, final projection ----
    hipMemsetAsync(fsum, 0, (size_t)NN * 256 * 4, stream);
    edge_to_node<<<NE / 4, 256, 0, stream>>>(feats, dst, fsum);
    {
        const long total = (long)NN * 416;
        build_finalA<<<(int)((total + 255) / 256), 256, 0, stream>>>(atom, fsum, finalA);
    }
    gemm_n256<3, true, false><<<NN / 32, 256, 0, stream>>>(finalA, Wo, bo, nullptr,
                                                           d_out, NN, 416, 389);
}

// Round 4
// 1774.810 us; speedup vs baseline: 5.3525x; 5.3525x over previous
//
#include <hip/hip_runtime.h>
#include <stdint.h>

#define NN 100000
#define NNP 100032          // NN padded to multiple of 64
#define NE 200000
#define NT 600000
#define HID 256

typedef __attribute__((ext_vector_type(8))) short bf16x8;
typedef __attribute__((ext_vector_type(4))) float f32x4;

__device__ __forceinline__ float bf2f(unsigned short u) {
    union { unsigned int i; float f; } x; x.i = ((unsigned int)u) << 16; return x.f;
}
__device__ __forceinline__ unsigned short f2bf(float f) {
    union { float f; unsigned int i; } x; x.f = f;
    unsigned int r = (x.i + 0x7FFFu + ((x.i >> 16) & 1u)) >> 16;
    return (unsigned short)r;
}

// swizzled byte offset into a [rows][32 bf16] LDS tile (64B rows, 4x16B slots)
// applied identically at ds_write (staging) and ds_read (fragments)
__device__ __forceinline__ int swz(int row, int cg) {
    return row * 64 + ((cg ^ ((row >> 1) & 3)) << 4);
}

// ---------------------------------------------------------------------------
// MFMA bf16 GEMM: C[M][256] = post(A[Mpad][Kpad] @ BT[256][Kpad]^T)
// FLAGS: 1 relu, 2 +bias(before relu), 4 +res bf16(after relu). CBF: C bf16.
// block = 256 thr (4 waves), tile BM=64 x BN=256, BK=32.
// ---------------------------------------------------------------------------
template<int FLAGS, bool CBF>
__global__ __launch_bounds__(256)
void mfma_gemm(const unsigned short* __restrict__ A,
               const unsigned short* __restrict__ BT,
               const float* __restrict__ bias,
               const unsigned short* __restrict__ res,
               void* __restrict__ Cv, int Mreal, int Kpad)
{
    __shared__ alignas(16) unsigned short Asl[64 * 32];
    __shared__ alignas(16) unsigned short Bsl[256 * 32];

    const int t    = threadIdx.x;
    const int lane = t & 63;
    const int wv   = t >> 6;
    const int row0 = blockIdx.x * 64;
    const int l15  = lane & 15;
    const int lk   = lane >> 4;

    f32x4 acc[4][4];
#pragma unroll
    for (int i = 0; i < 4; ++i)
#pragma unroll
        for (int j = 0; j < 4; ++j) acc[i][j] = (f32x4){0.f, 0.f, 0.f, 0.f};

    const int srow = t >> 2;    // staging row 0..63
    const int scg  = t & 3;     // staging 16B col-group

    for (int k0 = 0; k0 < Kpad; k0 += 32) {
        {
            const bf16x8 av = *(const bf16x8*)(A + (size_t)(row0 + srow) * Kpad + k0 + scg * 8);
            *(bf16x8*)((char*)Asl + swz(srow, scg)) = av;
        }
#pragma unroll
        for (int i = 0; i < 4; ++i) {
            const int n = srow + i * 64;
            const bf16x8 bv = *(const bf16x8*)(BT + (size_t)n * Kpad + k0 + scg * 8);
            *(bf16x8*)((char*)Bsl + swz(n, scg)) = bv;
        }
        __syncthreads();

        bf16x8 af[4], bfg[4];
#pragma unroll
        for (int mi = 0; mi < 4; ++mi)
            af[mi] = *(const bf16x8*)((const char*)Asl + swz(mi * 16 + l15, lk));
#pragma unroll
        for (int ni = 0; ni < 4; ++ni)
            bfg[ni] = *(const bf16x8*)((const char*)Bsl + swz(wv * 64 + ni * 16 + l15, lk));
#pragma unroll
        for (int mi = 0; mi < 4; ++mi)
#pragma unroll
            for (int ni = 0; ni < 4; ++ni)
                acc[mi][ni] = __builtin_amdgcn_mfma_f32_16x16x32_bf16(
                    af[mi], bfg[ni], acc[mi][ni], 0, 0, 0);
        __syncthreads();
    }

    // epilogue: D col=l&15, row=(l>>4)*4+reg
#pragma unroll
    for (int mi = 0; mi < 4; ++mi) {
#pragma unroll
        for (int r = 0; r < 4; ++r) {
            const int row = row0 + mi * 16 + lk * 4 + r;
            if (row >= Mreal) continue;
#pragma unroll
            for (int ni = 0; ni < 4; ++ni) {
                const int col = wv * 64 + ni * 16 + l15;
                float o = acc[mi][ni][r];
                if (FLAGS & 2) o += bias[col];
                if (FLAGS & 1) o = fmaxf(o, 0.f);
                if (FLAGS & 4) o += bf2f(res[(size_t)row * HID + col]);
                if (CBF) ((unsigned short*)Cv)[(size_t)row * HID + col] = f2bf(o);
                else     ((float*)Cv)[(size_t)row * HID + col] = o;
            }
        }
    }
}

// ---------------------------------------------------------------------------
__global__ __launch_bounds__(256)
void wconv(const float* __restrict__ W, unsigned short* __restrict__ BT,
           int Kreal, int Kpad)
{
    const int idx = blockIdx.x * 256 + threadIdx.x;
    const int n = idx / Kpad, kp = idx - n * Kpad;
    float v = (kp < Kreal) ? W[(size_t)kp * HID + n] : 0.f;
    BT[idx] = f2bf(v);
}

// ---------------------------------------------------------------------------
__global__ __launch_bounds__(256)
void build_initA(const float* __restrict__ atom, const float* __restrict__ edge,
                 const int* __restrict__ src, unsigned short* __restrict__ out)
{
    const long total = (long)NE * 160;
    long idx = (long)blockIdx.x * blockDim.x + threadIdx.x;
    if (idx >= total) return;
    const int e = (int)(idx / 160);
    const int c = (int)(idx - (long)e * 160);
    float v = 0.f;
    if (c < 133)      v = atom[(size_t)src[e] * 133 + c];
    else if (c < 147) v = edge[(size_t)e * 14 + (c - 133)];
    out[idx] = f2bf(v);
}

// ---------------------------------------------------------------------------
__global__ __launch_bounds__(256)
void build_finalA(const float* __restrict__ atom, const float* __restrict__ fsum,
                  unsigned short* __restrict__ out)
{
    const long total = (long)NNP * 416;
    long idx = (long)blockIdx.x * blockDim.x + threadIdx.x;
    if (idx >= total) return;
    const int n = (int)(idx / 416);
    const int c = (int)(idx - (long)n * 416);
    float v = 0.f;
    if (n < NN) {
        if (c < 133)      v = atom[(size_t)n * 133 + c];
        else if (c < 389) v = fsum[(size_t)n * 256 + (c - 133)];
    }
    out[idx] = f2bf(v);
}

// ---------------------------------------------------------------------------
// CSR build: histogram, 3-kernel exclusive scan, cursor copy, fill
// ---------------------------------------------------------------------------
__global__ __launch_bounds__(256)
void count_keys(const int* __restrict__ key, int n, int nkeys, int* __restrict__ cnt)
{
    const int i = blockIdx.x * 256 + threadIdx.x;
    if (i < n) {
        const int kk = key[i];
        if ((unsigned)kk < (unsigned)nkeys) atomicAdd(&cnt[kk], 1);
    }
}

__global__ __launch_bounds__(256)
void fill_lists(const int* __restrict__ key, int n, int nkeys, int cap,
                int* __restrict__ cur, int* __restrict__ list)
{
    const int i = blockIdx.x * 256 + threadIdx.x;
    if (i < n) {
        const int kk = key[i];
        if ((unsigned)kk >= (unsigned)nkeys) return;
        const int pos = atomicAdd(&cur[kk], 1);
        if ((unsigned)pos < (unsigned)cap) list[pos] = i;
    }
}

// per-block (1024 elems) exclusive scan; partials out
__global__ __launch_bounds__(256)
void scan1(const int* __restrict__ in, int n, int* __restrict__ excl,
           int* __restrict__ part)
{
    __shared__ int sh[256];
    const int t = threadIdx.x;
    const int base = blockIdx.x * 1024 + t * 4;
    int v[4]; int s = 0;
#pragma unroll
    for (int j = 0; j < 4; ++j) { v[j] = (base + j < n) ? in[base + j] : 0; s += v[j]; }
    sh[t] = s; __syncthreads();
    for (int off = 1; off < 256; off <<= 1) {
        int x = (t >= off) ? sh[t - off] : 0;
        __syncthreads();
        sh[t] += x;
        __syncthreads();
    }
    int ex = sh[t] - s;
#pragma unroll
    for (int j = 0; j < 4; ++j) { if (base + j < n) excl[base + j] = ex; ex += v[j]; }
    if (t == 255) part[blockIdx.x] = sh[255];
}

// single-block exclusive scan of partials (nparts <= 256)
__global__ __launch_bounds__(256)
void scan2(int* __restrict__ part, int nparts)
{
    __shared__ int sh[256];
    const int t = threadIdx.x;
    const int v = (t < nparts) ? part[t] : 0;
    sh[t] = v; __syncthreads();
    for (int off = 1; off < 256; off <<= 1) {
        int x = (t >= off) ? sh[t - off] : 0;
        __syncthreads();
        sh[t] += x;
        __syncthreads();
    }
    if (t < nparts) part[t] = sh[t] - v;
}

// offs[i] = excl[i] + part[i/1024]; offs[n] = total   (counts NOT aliased)
__global__ __launch_bounds__(256)
void scan3(const int* __restrict__ excl, const int* __restrict__ part,
           const int* __restrict__ counts, int n, int* __restrict__ offs)
{
    const int i = blockIdx.x * 256 + threadIdx.x;
    if (i >= n) return;
    const int v = excl[i] + part[i >> 10];
    offs[i] = v;
    if (i == n - 1) offs[n] = v + counts[i];
}

__global__ __launch_bounds__(256)
void copy_off(const int* __restrict__ offs, int n, int* __restrict__ cur)
{
    const int i = blockIdx.x * 256 + threadIdx.x;
    if (i < n) cur[i] = offs[i];
}

// ---------------------------------------------------------------------------
// Fused attention gather: one wave per edge e.
// ---------------------------------------------------------------------------
__global__ __launch_bounds__(256)
void gather_v(const unsigned short* __restrict__ q, const unsigned short* __restrict__ k,
              const unsigned short* __restrict__ v,
              const int* __restrict__ toff, const int* __restrict__ tlist,
              const int* __restrict__ idx_kj,
              unsigned short* __restrict__ vc)
{
    const int w    = (int)(((long)blockIdx.x * blockDim.x + threadIdx.x) >> 6);
    const int lane = threadIdx.x & 63;
    if (w >= NE) return;
    int beg = toff[w], end = toff[w + 1];
    if (beg < 0) beg = 0;
    if (end > NT) end = NT;
    const ushort4 kv = *(const ushort4*)(k + (size_t)w * HID + lane * 4);
    const float k0 = bf2f(kv.x), k1 = bf2f(kv.y), k2 = bf2f(kv.z), k3 = bf2f(kv.w);
    float a0 = 0.f, a1 = 0.f, a2 = 0.f, a3 = 0.f, den = 0.f;
    for (int p = beg; p < end; ++p) {
        const int tt = tlist[p];
        if ((unsigned)tt >= (unsigned)NT) continue;
        const int kj = idx_kj[tt];
        if ((unsigned)kj >= (unsigned)NE) continue;
        const ushort4 qv = *(const ushort4*)(q + (size_t)kj * HID + lane * 4);
        float s = bf2f(qv.x) * k0 + bf2f(qv.y) * k1 + bf2f(qv.z) * k2 + bf2f(qv.w) * k3;
        s += __shfl_xor(s, 1);
        s += __shfl_xor(s, 2);
        s += __shfl_xor(s, 4);
        const float lr = (s > 0.f) ? s : 0.2f * s;
        const float a  = __expf(lr);
        den += a;
        const ushort4 vv = *(const ushort4*)(v + (size_t)kj * HID + lane * 4);
        a0 += a * bf2f(vv.x); a1 += a * bf2f(vv.y);
        a2 += a * bf2f(vv.z); a3 += a * bf2f(vv.w);
    }
    const float inv = (den != 0.f) ? 1.f / den : 0.f;
    ushort4 o;
    o.x = f2bf(a0 * inv); o.y = f2bf(a1 * inv);
    o.z = f2bf(a2 * inv); o.w = f2bf(a3 * inv);
    *(ushort4*)(vc + (size_t)w * HID + lane * 4) = o;
}

// ---------------------------------------------------------------------------
__global__ __launch_bounds__(256)
void gather_node(const unsigned short* __restrict__ feats,
                 const int* __restrict__ noff, const int* __restrict__ nlist,
                 float* __restrict__ fsum)
{
    const int w    = (int)(((long)blockIdx.x * blockDim.x + threadIdx.x) >> 6);
    const int lane = threadIdx.x & 63;
    if (w >= NN) return;
    int beg = noff[w], end = noff[w + 1];
    if (beg < 0) beg = 0;
    if (end > NE) end = NE;
    float a0 = 0.f, a1 = 0.f, a2 = 0.f, a3 = 0.f;
    for (int p = beg; p < end; ++p) {
        const int e = nlist[p];
        if ((unsigned)e >= (unsigned)NE) continue;
        const ushort4 f = *(const ushort4*)(feats + (size_t)e * HID + lane * 4);
        a0 += bf2f(f.x); a1 += bf2f(f.y); a2 += bf2f(f.z); a3 += bf2f(f.w);
    }
    float4 o = make_float4(a0, a1, a2, a3);
    *(float4*)(fsum + (size_t)w * HID + lane * 4) = o;
}

// ---------------------------------------------------------------------------
extern "C" void kernel_launch(void* const* d_in, const int* in_sizes, int n_in,
                              void* d_out, int out_size, void* d_ws, size_t ws_size,
                              hipStream_t stream)
{
    const float* atom = (const float*)d_in[0];
    const float* edge = (const float*)d_in[1];
    const float* W_i  = (const float*)d_in[2];
    const float* Wq   = (const float*)d_in[3];
    const float* Wk   = (const float*)d_in[4];
    const float* Wv   = (const float*)d_in[5];
    const float* L1w  = (const float*)d_in[6];
    const float* L1b  = (const float*)d_in[7];
    const float* L2w  = (const float*)d_in[8];
    const float* L2b  = (const float*)d_in[9];
    const float* Wo   = (const float*)d_in[10];
    const float* bo   = (const float*)d_in[11];
    const int* src    = (const int*)d_in[12];
    const int* dst    = (const int*)d_in[13];
    const int* idx_kj = (const int*)d_in[14];
    const int* idx_ji = (const int*)d_in[15];

    const size_t RB = (size_t)NE * HID * 2;   // 102,400,000 B
    char* ws = (char*)d_ws;
    unsigned short* feats = (unsigned short*)(ws);
    unsigned short* qb    = (unsigned short*)(ws + RB);
    unsigned short* kb    = (unsigned short*)(ws + 2 * RB);
    unsigned short* vb    = (unsigned short*)d_out;     // NE*256 bf16 == d_out bytes
    unsigned short* vc    = feats;                      // v_clone overlays feats
    unsigned short* initA = qb;
    unsigned short* h1    = kb;
    float*          fsum  = (float*)(ws + RB);          // NN*256 f32 == RB bytes
    unsigned short* finalA = kb;

    char* p = ws + 3 * RB;
    int* trip_off  = (int*)p; p += 800016;   // (NE+1)*4 rounded
    int* trip_cur  = (int*)p; p += 800016;   // counts, then cursor
    int* trip_list = (int*)p; p += 2400000;  // NT*4
    int* node_off  = (int*)p; p += 400016;   // (NN+1)*4 rounded
    int* node_cur  = (int*)p; p += 400016;
    int* node_list = (int*)p; p += 800000;   // NE*4
    int* tmp_excl  = (int*)p; p += 800016;
    int* partials  = (int*)p; p += 1024;
    unsigned short* wiT = (unsigned short*)p; p += (size_t)256 * 160 * 2;
    unsigned short* wT[10]; // q0,k0,v0,l1_0,l2_0,q1,k1,v1,l1_1,l2_1
    for (int i = 0; i < 10; ++i) { wT[i] = (unsigned short*)p; p += (size_t)256 * 256 * 2; }
    unsigned short* woT = (unsigned short*)p; p += (size_t)256 * 416 * 2;
    const size_t NEEDED = (size_t)(p - ws);
    if (ws_size < NEEDED) return;

    // ---- weight convert/transpose/pad (bf16) ----
    wconv<<<160, 256, 0, stream>>>(W_i, wiT, 147, 160);
    for (int l = 0; l < 2; ++l) {
        wconv<<<256, 256, 0, stream>>>(Wq  + (size_t)l * 65536, wT[l * 5 + 0], 256, 256);
        wconv<<<256, 256, 0, stream>>>(Wk  + (size_t)l * 65536, wT[l * 5 + 1], 256, 256);
        wconv<<<256, 256, 0, stream>>>(Wv  + (size_t)l * 65536, wT[l * 5 + 2], 256, 256);
        wconv<<<256, 256, 0, stream>>>(L1w + (size_t)l * 65536, wT[l * 5 + 3], 256, 256);
        wconv<<<256, 256, 0, stream>>>(L2w + (size_t)l * 65536, wT[l * 5 + 4], 256, 256);
    }
    wconv<<<416, 256, 0, stream>>>(Wo, woT, 389, 416);

    // ---- CSR build (triplets by idx_ji; edges by dst) ----
    hipMemsetAsync(trip_cur, 0, (size_t)NE * 4, stream);
    hipMemsetAsync(node_cur, 0, (size_t)NN * 4, stream);
    count_keys<<<(NT + 255) / 256, 256, 0, stream>>>(idx_ji, NT, NE, trip_cur);
    count_keys<<<(NE + 255) / 256, 256, 0, stream>>>(dst, NE, NN, node_cur);

    scan1<<<(NE + 1023) / 1024, 256, 0, stream>>>(trip_cur, NE, tmp_excl, partials);
    scan2<<<1, 256, 0, stream>>>(partials, (NE + 1023) / 1024);
    scan3<<<(NE + 255) / 256, 256, 0, stream>>>(tmp_excl, partials, trip_cur, NE, trip_off);
    copy_off<<<(NE + 255) / 256, 256, 0, stream>>>(trip_off, NE, trip_cur);
    fill_lists<<<(NT + 255) / 256, 256, 0, stream>>>(idx_ji, NT, NE, NT, trip_cur, trip_list);

    scan1<<<(NN + 1023) / 1024, 256, 0, stream>>>(node_cur, NN, tmp_excl, partials);
    scan2<<<1, 256, 0, stream>>>(partials, (NN + 1023) / 1024);
    scan3<<<(NN + 255) / 256, 256, 0, stream>>>(tmp_excl, partials, node_cur, NN, node_off);
    copy_off<<<(NN + 255) / 256, 256, 0, stream>>>(node_off, NN, node_cur);
    fill_lists<<<(NE + 255) / 256, 256, 0, stream>>>(dst, NE, NN, NE, node_cur, node_list);

    // ---- init: feats = relu(concat(atom[src], edge) @ W_i) ----
    {
        const long total = (long)NE * 160;
        build_initA<<<(int)((total + 255) / 256), 256, 0, stream>>>(atom, edge, src, initA);
    }
    mfma_gemm<1, true><<<NE / 64, 256, 0, stream>>>(initA, wiT, nullptr, nullptr, feats, NE, 160);

    // ---- 2 attention layers ----
    for (int l = 0; l < 2; ++l) {
        const float* l1b = L1b + (size_t)l * 256;
        const float* l2b = L2b + (size_t)l * 256;
        mfma_gemm<0, true><<<NE / 64, 256, 0, stream>>>(feats, wT[l * 5 + 0], nullptr, nullptr, qb, NE, 256);
        mfma_gemm<0, true><<<NE / 64, 256, 0, stream>>>(feats, wT[l * 5 + 1], nullptr, nullptr, kb, NE, 256);
        mfma_gemm<0, true><<<NE / 64, 256, 0, stream>>>(feats, wT[l * 5 + 2], nullptr, nullptr, vb, NE, 256);

        gather_v<<<NE / 4, 256, 0, stream>>>(qb, kb, vb, trip_off, trip_list, idx_kj, vc);

        // h1 = relu(vc @ L1 + b1); feats = v + relu(h1 @ L2 + b2)
        mfma_gemm<3, true><<<NE / 64, 256, 0, stream>>>(vc, wT[l * 5 + 3], l1b, nullptr, h1, NE, 256);
        mfma_gemm<7, true><<<NE / 64, 256, 0, stream>>>(h1, wT[l * 5 + 4], l2b, vb, feats, NE, 256);
    }

    // ---- edge -> node gather, final projection ----
    gather_node<<<NN / 4, 256, 0, stream>>>(feats, node_off, node_list, fsum);
    {
        const long total = (long)NNP * 416;
        build_finalA<<<(int)((total + 255) / 256), 256, 0, stream>>>(atom, fsum, finalA);
    }
    mfma_gemm<3, false><<<NNP / 64, 256, 0, stream>>>(finalA, woT, bo, nullptr, d_out, NN, 416);
}

// Round 5
// 1564.342 us; speedup vs baseline: 6.0726x; 1.1345x over previous
//
#include <hip/hip_runtime.h>
#include <stdint.h>

#define NN 100000
#define NNP 100032          // NN padded to multiple of 64
#define NE 200000
#define NT 600000
#define HID 256

typedef __attribute__((ext_vector_type(8))) short bf16x8;
typedef __attribute__((ext_vector_type(4))) float f32x4;

__device__ __forceinline__ float bf2f(unsigned short u) {
    union { unsigned int i; float f; } x; x.i = ((unsigned int)u) << 16; return x.f;
}
__device__ __forceinline__ unsigned short f2bf(float f) {
    union { float f; unsigned int i; } x; x.f = f;
    unsigned int r = (x.i + 0x7FFFu + ((x.i >> 16) & 1u)) >> 16;
    return (unsigned short)r;
}

// async global->LDS, 16B per lane; LDS dest = uniform base + lane*16
__device__ __forceinline__ void gload16(const void* g, void* l) {
    __builtin_amdgcn_global_load_lds(
        (const __attribute__((address_space(1))) void*)g,
        (__attribute__((address_space(3))) void*)l, 16, 0, 0);
}

// ---------------------------------------------------------------------------
// MFMA bf16 GEMM: C[M][256] = post(A[Mpad][Kpad] @ BT[256][Kpad]^T)
// FLAGS: 1 relu, 2 +bias(before relu), 4 +res bf16(after relu). CBF: C bf16.
// block = 256 thr (4 waves), tile BM=64 x BN=256, BK=64, double-buffered
// global_load_lds staging. LDS rows are 64 bf16 = 128B = 8 x 16B chunks;
// swizzle: data for (row, chunk c) lives at LDS chunk (c ^ (row&7)).
// gload_lds writes linearly, so the SOURCE address is pre-swizzled
// (cg = chunk_lds ^ (row&7)) and ds_read applies the same XOR  [rule 21].
// ---------------------------------------------------------------------------
template<int FLAGS, bool CBF>
__global__ __launch_bounds__(256)
void mfma_gemm(const unsigned short* __restrict__ A,
               const unsigned short* __restrict__ BT,
               const float* __restrict__ bias,
               const unsigned short* __restrict__ res,
               void* __restrict__ Cv, int Mreal, int Kpad)
{
    __shared__ alignas(16) unsigned short Asl[2][64 * 64];     // 2 x 8 KB
    __shared__ alignas(16) unsigned short Bsl[2][256 * 64];    // 2 x 32 KB

    const int t    = threadIdx.x;
    const int lane = t & 63;
    const int wv   = t >> 6;
    const int row0 = blockIdx.x * 64;
    const int l15  = lane & 15;
    const int lk   = lane >> 4;

    f32x4 acc[4][4];
#pragma unroll
    for (int i = 0; i < 4; ++i)
#pragma unroll
        for (int j = 0; j < 4; ++j) acc[i][j] = (f32x4){0.f, 0.f, 0.f, 0.f};

    const int srow8 = lane >> 3;   // sub-row within an 8-row staging instr
    const int schk  = lane & 7;    // linear LDS chunk this lane fills

    // stage one K-tile (BK=64) into buffer buf: A 8 instrs, B 32 instrs
    auto stage = [&](int buf, int k0) {
#pragma unroll
        for (int j = 0; j < 2; ++j) {                 // A: instrs wv*2+j
            const int ii = wv * 2 + j;
            const int r  = ii * 8 + srow8;            // local row 0..63
            const int cg = schk ^ (r & 7);
            gload16(A + (size_t)(row0 + r) * Kpad + k0 + cg * 8,
                    &Asl[buf][ii * 512]);
        }
#pragma unroll
        for (int j = 0; j < 8; ++j) {                 // B: instrs wv*8+j
            const int ii = wv * 8 + j;
            const int r  = ii * 8 + srow8;            // B row = N col 0..255
            const int cg = schk ^ (r & 7);
            gload16(BT + (size_t)r * Kpad + k0 + cg * 8,
                    &Bsl[buf][ii * 512]);
        }
    };

    auto compute = [&](int buf) {
#pragma unroll
        for (int ks = 0; ks < 2; ++ks) {
            bf16x8 af[4], bfg[4];
#pragma unroll
            for (int mi = 0; mi < 4; ++mi) {
                const int r = mi * 16 + l15;
                const int c = ks * 4 + lk;
                af[mi] = *(const bf16x8*)((const char*)&Asl[buf][0]
                          + r * 128 + ((c ^ (r & 7)) << 4));
            }
#pragma unroll
            for (int ni = 0; ni < 4; ++ni) {
                const int r = wv * 64 + ni * 16 + l15;
                const int c = ks * 4 + lk;
                bfg[ni] = *(const bf16x8*)((const char*)&Bsl[buf][0]
                           + r * 128 + ((c ^ (r & 7)) << 4));
            }
#pragma unroll
            for (int mi = 0; mi < 4; ++mi)
#pragma unroll
                for (int ni = 0; ni < 4; ++ni)
                    acc[mi][ni] = __builtin_amdgcn_mfma_f32_16x16x32_bf16(
                        af[mi], bfg[ni], acc[mi][ni], 0, 0, 0);
        }
    };

    const int nt = Kpad >> 6;
    stage(0, 0);
    __syncthreads();                       // drains vmcnt -> tile 0 ready
    for (int tt = 0; tt < nt; ++tt) {
        const int cur = tt & 1;
        if (tt + 1 < nt) stage(cur ^ 1, (tt + 1) << 6);   // issue early
        compute(cur);                                      // hide load latency
        __syncthreads();                   // loads drained + reads done
    }

    // epilogue: D col=l&15, row=(l>>4)*4+reg
#pragma unroll
    for (int mi = 0; mi < 4; ++mi) {
#pragma unroll
        for (int r = 0; r < 4; ++r) {
            const int row = row0 + mi * 16 + lk * 4 + r;
            if (row >= Mreal) continue;
#pragma unroll
            for (int ni = 0; ni < 4; ++ni) {
                const int col = wv * 64 + ni * 16 + l15;
                float o = acc[mi][ni][r];
                if (FLAGS & 2) o += bias[col];
                if (FLAGS & 1) o = fmaxf(o, 0.f);
                if (FLAGS & 4) o += bf2f(res[(size_t)row * HID + col]);
                if (CBF) ((unsigned short*)Cv)[(size_t)row * HID + col] = f2bf(o);
                else     ((float*)Cv)[(size_t)row * HID + col] = o;
            }
        }
    }
}

// ---------------------------------------------------------------------------
// weight transpose/convert: BT[n][kp] = bf16(W[kp][n]); grid = Kpad blocks
// ---------------------------------------------------------------------------
__global__ __launch_bounds__(256)
void wconv(const float* __restrict__ W, unsigned short* __restrict__ BT,
           int Kreal, int Kpad)
{
    const int idx = blockIdx.x * 256 + threadIdx.x;
    const int n = idx / Kpad, kp = idx - n * Kpad;
    float v = (kp < Kreal) ? W[(size_t)kp * HID + n] : 0.f;
    BT[idx] = f2bf(v);
}

// 10 x (256x256) weights in one launch: y = l*5 + which
__global__ __launch_bounds__(256)
void wconv10(const float* __restrict__ Wq, const float* __restrict__ Wk,
             const float* __restrict__ Wv, const float* __restrict__ L1w,
             const float* __restrict__ L2w, unsigned short* __restrict__ outbase)
{
    const int y = blockIdx.y;
    const int l = y / 5, which = y - l * 5;
    const float* src;
    switch (which) {
        case 0: src = Wq;  break;
        case 1: src = Wk;  break;
        case 2: src = Wv;  break;
        case 3: src = L1w; break;
        default: src = L2w; break;
    }
    src += (size_t)l * 65536;
    const int idx = blockIdx.x * 256 + threadIdx.x;   // 0..65535
    const int n = idx >> 8, kp = idx & 255;
    outbase[(size_t)y * 65536 + idx] = f2bf(src[(size_t)kp * HID + n]);
}

// ---------------------------------------------------------------------------
// initA[e][0:133]=atom[src[e]], [133:147]=edge[e], [147:192)=0   (bf16)
// ---------------------------------------------------------------------------
__global__ __launch_bounds__(256)
void build_initA(const float* __restrict__ atom, const float* __restrict__ edge,
                 const int* __restrict__ src, unsigned short* __restrict__ out)
{
    const long total = (long)NE * 192;
    long idx = (long)blockIdx.x * blockDim.x + threadIdx.x;
    if (idx >= total) return;
    const int e = (int)(idx / 192);
    const int c = (int)(idx - (long)e * 192);
    float v = 0.f;
    if (c < 133)      v = atom[(size_t)src[e] * 133 + c];
    else if (c < 147) v = edge[(size_t)e * 14 + (c - 133)];
    out[idx] = f2bf(v);
}

// ---------------------------------------------------------------------------
// finalA[n][0:133]=atom[n], [133:389]=fsum[n], [389:448)=0, NNP rows (bf16)
// ---------------------------------------------------------------------------
__global__ __launch_bounds__(256)
void build_finalA(const float* __restrict__ atom, const float* __restrict__ fsum,
                  unsigned short* __restrict__ out)
{
    const long total = (long)NNP * 448;
    long idx = (long)blockIdx.x * blockDim.x + threadIdx.x;
    if (idx >= total) return;
    const int n = (int)(idx / 448);
    const int c = (int)(idx - (long)n * 448);
    float v = 0.f;
    if (n < NN) {
        if (c < 133)      v = atom[(size_t)n * 133 + c];
        else if (c < 389) v = fsum[(size_t)n * 256 + (c - 133)];
    }
    out[idx] = f2bf(v);
}

// ---------------------------------------------------------------------------
// CSR build: histogram, 3-kernel exclusive scan, cursor copy, fill
// ---------------------------------------------------------------------------
__global__ __launch_bounds__(256)
void count_keys(const int* __restrict__ key, int n, int nkeys, int* __restrict__ cnt)
{
    const int i = blockIdx.x * 256 + threadIdx.x;
    if (i < n) {
        const int kk = key[i];
        if ((unsigned)kk < (unsigned)nkeys) atomicAdd(&cnt[kk], 1);
    }
}

__global__ __launch_bounds__(256)
void fill_lists(const int* __restrict__ key, int n, int nkeys, int cap,
                int* __restrict__ cur, int* __restrict__ list)
{
    const int i = blockIdx.x * 256 + threadIdx.x;
    if (i < n) {
        const int kk = key[i];
        if ((unsigned)kk >= (unsigned)nkeys) return;
        const int pos = atomicAdd(&cur[kk], 1);
        if ((unsigned)pos < (unsigned)cap) list[pos] = i;
    }
}

__global__ __launch_bounds__(256)
void scan1(const int* __restrict__ in, int n, int* __restrict__ excl,
           int* __restrict__ part)
{
    __shared__ int sh[256];
    const int t = threadIdx.x;
    const int base = blockIdx.x * 1024 + t * 4;
    int v[4]; int s = 0;
#pragma unroll
    for (int j = 0; j < 4; ++j) { v[j] = (base + j < n) ? in[base + j] : 0; s += v[j]; }
    sh[t] = s; __syncthreads();
    for (int off = 1; off < 256; off <<= 1) {
        int x = (t >= off) ? sh[t - off] : 0;
        __syncthreads();
        sh[t] += x;
        __syncthreads();
    }
    int ex = sh[t] - s;
#pragma unroll
    for (int j = 0; j < 4; ++j) { if (base + j < n) excl[base + j] = ex; ex += v[j]; }
    if (t == 255) part[blockIdx.x] = sh[255];
}

__global__ __launch_bounds__(256)
void scan2(int* __restrict__ part, int nparts)
{
    __shared__ int sh[256];
    const int t = threadIdx.x;
    const int v = (t < nparts) ? part[t] : 0;
    sh[t] = v; __syncthreads();
    for (int off = 1; off < 256; off <<= 1) {
        int x = (t >= off) ? sh[t - off] : 0;
        __syncthreads();
        sh[t] += x;
        __syncthreads();
    }
    if (t < nparts) part[t] = sh[t] - v;
}

__global__ __launch_bounds__(256)
void scan3(const int* __restrict__ excl, const int* __restrict__ part,
           const int* __restrict__ counts, int n, int* __restrict__ offs)
{
    const int i = blockIdx.x * 256 + threadIdx.x;
    if (i >= n) return;
    const int v = excl[i] + part[i >> 10];
    offs[i] = v;
    if (i == n - 1) offs[n] = v + counts[i];
}

__global__ __launch_bounds__(256)
void copy_off(const int* __restrict__ offs, int n, int* __restrict__ cur)
{
    const int i = blockIdx.x * 256 + threadIdx.x;
    if (i < n) cur[i] = offs[i];
}

// ---------------------------------------------------------------------------
// Fused attention gather: 32 lanes per edge (2 edges/wave), bf16x8 loads.
// head h = dim/32 -> 4 lanes per head -> 2-shuffle reduce.
// Software-pipelined tlist->idx_kj chain.
// ---------------------------------------------------------------------------
__global__ __launch_bounds__(256)
void gather_v(const unsigned short* __restrict__ q, const unsigned short* __restrict__ k,
              const unsigned short* __restrict__ v,
              const int* __restrict__ toff, const int* __restrict__ tlist,
              const int* __restrict__ idx_kj,
              unsigned short* __restrict__ vc)
{
    const long gtid = (long)blockIdx.x * blockDim.x + threadIdx.x;
    const int w    = (int)(gtid >> 5);          // edge id (one 32-lane half)
    const int lane = threadIdx.x & 31;
    if (w >= NE) return;
    int beg = toff[w], end = toff[w + 1];
    if (beg < 0) beg = 0;
    if (end > NT) end = NT;

    const bf16x8 kv = *(const bf16x8*)(k + (size_t)w * HID + lane * 8);
    float kf[8];
#pragma unroll
    for (int j = 0; j < 8; ++j) kf[j] = bf2f((unsigned short)kv[j]);

    float av[8];
#pragma unroll
    for (int j = 0; j < 8; ++j) av[j] = 0.f;
    float den = 0.f;

    int kj_next = -1;
    if (beg < end) {
        const int tt = tlist[beg];
        kj_next = ((unsigned)tt < (unsigned)NT) ? idx_kj[tt] : -1;
    }
    for (int p = beg; p < end; ++p) {
        const int kj = kj_next;
        if (p + 1 < end) {
            const int tt = tlist[p + 1];
            kj_next = ((unsigned)tt < (unsigned)NT) ? idx_kj[tt] : -1;
        }
        if ((unsigned)kj >= (unsigned)NE) continue;
        const bf16x8 qv = *(const bf16x8*)(q + (size_t)kj * HID + lane * 8);
        float s = 0.f;
#pragma unroll
        for (int j = 0; j < 8; ++j) s += bf2f((unsigned short)qv[j]) * kf[j];
        s += __shfl_xor(s, 1);
        s += __shfl_xor(s, 2);               // 4-lane head reduce (d=32)
        const float lr = (s > 0.f) ? s : 0.2f * s;
        const float a  = __expf(lr);
        den += a;
        const bf16x8 vv = *(const bf16x8*)(v + (size_t)kj * HID + lane * 8);
#pragma unroll
        for (int j = 0; j < 8; ++j) av[j] += a * bf2f((unsigned short)vv[j]);
    }
    const float inv = (den != 0.f) ? 1.f / den : 0.f;
    bf16x8 o;
#pragma unroll
    for (int j = 0; j < 8; ++j) o[j] = (short)f2bf(av[j] * inv);
    *(bf16x8*)(vc + (size_t)w * HID + lane * 8) = o;
}

// ---------------------------------------------------------------------------
__global__ __launch_bounds__(256)
void gather_node(const unsigned short* __restrict__ feats,
                 const int* __restrict__ noff, const int* __restrict__ nlist,
                 float* __restrict__ fsum)
{
    const int w    = (int)(((long)blockIdx.x * blockDim.x + threadIdx.x) >> 6);
    const int lane = threadIdx.x & 63;
    if (w >= NN) return;
    int beg = noff[w], end = noff[w + 1];
    if (beg < 0) beg = 0;
    if (end > NE) end = NE;
    float a0 = 0.f, a1 = 0.f, a2 = 0.f, a3 = 0.f;
    for (int p = beg; p < end; ++p) {
        const int e = nlist[p];
        if ((unsigned)e >= (unsigned)NE) continue;
        const ushort4 f = *(const ushort4*)(feats + (size_t)e * HID + lane * 4);
        a0 += bf2f(f.x); a1 += bf2f(f.y); a2 += bf2f(f.z); a3 += bf2f(f.w);
    }
    float4 o = make_float4(a0, a1, a2, a3);
    *(float4*)(fsum + (size_t)w * HID + lane * 4) = o;
}

// ---------------------------------------------------------------------------
extern "C" void kernel_launch(void* const* d_in, const int* in_sizes, int n_in,
                              void* d_out, int out_size, void* d_ws, size_t ws_size,
                              hipStream_t stream)
{
    const float* atom = (const float*)d_in[0];
    const float* edge = (const float*)d_in[1];
    const float* W_i  = (const float*)d_in[2];
    const float* Wq   = (const float*)d_in[3];
    const float* Wk   = (const float*)d_in[4];
    const float* Wv   = (const float*)d_in[5];
    const float* L1w  = (const float*)d_in[6];
    const float* L1b  = (const float*)d_in[7];
    const float* L2w  = (const float*)d_in[8];
    const float* L2b  = (const float*)d_in[9];
    const float* Wo   = (const float*)d_in[10];
    const float* bo   = (const float*)d_in[11];
    const int* src    = (const int*)d_in[12];
    const int* dst    = (const int*)d_in[13];
    const int* idx_kj = (const int*)d_in[14];
    const int* idx_ji = (const int*)d_in[15];

    const size_t RB = (size_t)NE * HID * 2;   // 102,400,000 B
    char* ws = (char*)d_ws;
    unsigned short* feats = (unsigned short*)(ws);
    unsigned short* qb    = (unsigned short*)(ws + RB);
    unsigned short* kb    = (unsigned short*)(ws + 2 * RB);
    unsigned short* vb    = (unsigned short*)d_out;     // NE*256 bf16 == d_out bytes
    unsigned short* vc    = feats;                      // v_clone overlays feats
    unsigned short* initA = qb;                         // NE*192 bf16 = 76.8MB < RB
    unsigned short* h1    = kb;
    float*          fsum  = (float*)(ws + RB);          // NN*256 f32 == RB bytes
    unsigned short* finalA = kb;                        // NNP*448 bf16 = 89.6MB < RB

    char* p = ws + 3 * RB;
    int* trip_off  = (int*)p; p += 800016;   // (NE+1)*4 rounded
    int* trip_cur  = (int*)p; p += 800016;
    int* trip_list = (int*)p; p += 2400000;  // NT*4
    int* node_off  = (int*)p; p += 400016;
    int* node_cur  = (int*)p; p += 400016;
    int* node_list = (int*)p; p += 800000;   // NE*4
    int* tmp_excl  = (int*)p; p += 800016;
    int* partials  = (int*)p; p += 1024;
    unsigned short* wiT = (unsigned short*)p; p += (size_t)256 * 192 * 2;
    unsigned short* wT0 = (unsigned short*)p; p += (size_t)10 * 65536 * 2; // 10 weights
    unsigned short* woT = (unsigned short*)p; p += (size_t)256 * 448 * 2;
    const size_t NEEDED = (size_t)(p - ws);
    if (ws_size < NEEDED) return;
    auto wT = [&](int i) { return wT0 + (size_t)i * 65536; };

    // ---- weight convert/transpose/pad (bf16) ----
    wconv<<<192, 256, 0, stream>>>(W_i, wiT, 147, 192);
    wconv10<<<dim3(256, 10), 256, 0, stream>>>(Wq, Wk, Wv, L1w, L2w, wT0);
    wconv<<<448, 256, 0, stream>>>(Wo, woT, 389, 448);

    // ---- CSR build (triplets by idx_ji; edges by dst) ----
    hipMemsetAsync(trip_cur, 0, (size_t)NE * 4, stream);
    hipMemsetAsync(node_cur, 0, (size_t)NN * 4, stream);
    count_keys<<<(NT + 255) / 256, 256, 0, stream>>>(idx_ji, NT, NE, trip_cur);
    count_keys<<<(NE + 255) / 256, 256, 0, stream>>>(dst, NE, NN, node_cur);

    scan1<<<(NE + 1023) / 1024, 256, 0, stream>>>(trip_cur, NE, tmp_excl, partials);
    scan2<<<1, 256, 0, stream>>>(partials, (NE + 1023) / 1024);
    scan3<<<(NE + 255) / 256, 256, 0, stream>>>(tmp_excl, partials, trip_cur, NE, trip_off);
    copy_off<<<(NE + 255) / 256, 256, 0, stream>>>(trip_off, NE, trip_cur);
    fill_lists<<<(NT + 255) / 256, 256, 0, stream>>>(idx_ji, NT, NE, NT, trip_cur, trip_list);

    scan1<<<(NN + 1023) / 1024, 256, 0, stream>>>(node_cur, NN, tmp_excl, partials);
    scan2<<<1, 256, 0, stream>>>(partials, (NN + 1023) / 1024);
    scan3<<<(NN + 255) / 256, 256, 0, stream>>>(tmp_excl, partials, node_cur, NN, node_off);
    copy_off<<<(NN + 255) / 256, 256, 0, stream>>>(node_off, NN, node_cur);
    fill_lists<<<(NE + 255) / 256, 256, 0, stream>>>(dst, NE, NN, NE, node_cur, node_list);

    // ---- init: feats = relu(concat(atom[src], edge) @ W_i) ----
    {
        const long total = (long)NE * 192;
        build_initA<<<(int)((total + 255) / 256), 256, 0, stream>>>(atom, edge, src, initA);
    }
    mfma_gemm<1, true><<<NE / 64, 256, 0, stream>>>(initA, wiT, nullptr, nullptr, feats, NE, 192);

    // ---- 2 attention layers ----
    for (int l = 0; l < 2; ++l) {
        const float* l1b = L1b + (size_t)l * 256;
        const float* l2b = L2b + (size_t)l * 256;
        mfma_gemm<0, true><<<NE / 64, 256, 0, stream>>>(feats, wT(l * 5 + 0), nullptr, nullptr, qb, NE, 256);
        mfma_gemm<0, true><<<NE / 64, 256, 0, stream>>>(feats, wT(l * 5 + 1), nullptr, nullptr, kb, NE, 256);
        mfma_gemm<0, true><<<NE / 64, 256, 0, stream>>>(feats, wT(l * 5 + 2), nullptr, nullptr, vb, NE, 256);

        gather_v<<<(NE * 32) / 256, 256, 0, stream>>>(qb, kb, vb, trip_off, trip_list, idx_kj, vc);

        // h1 = relu(vc @ L1 + b1); feats = v + relu(h1 @ L2 + b2)
        mfma_gemm<3, true><<<NE / 64, 256, 0, stream>>>(vc, wT(l * 5 + 3), l1b, nullptr, h1, NE, 256);
        mfma_gemm<7, true><<<NE / 64, 256, 0, stream>>>(h1, wT(l * 5 + 4), l2b, vb, feats, NE, 256);
    }

    // ---- edge -> node gather, final projection ----
    gather_node<<<NN / 4, 256, 0, stream>>>(feats, node_off, node_list, fsum);
    {
        const long total = (long)NNP * 448;
        build_finalA<<<(int)((total + 255) / 256), 256, 0, stream>>>(atom, fsum, finalA);
    }
    mfma_gemm<3, false><<<NNP / 64, 256, 0, stream>>>(finalA, woT, bo, nullptr, d_out, NN, 448);
}

// Round 6
// 1428.381 us; speedup vs baseline: 6.6506x; 1.0952x over previous
//
#include <hip/hip_runtime.h>
#include <stdint.h>

#define NN 100000
#define NNP 100032          // NN padded to multiple of 64
#define NE 200000
#define NEP 200064          // NE padded to multiple of 128
#define NT 600000
#define HID 256

typedef __attribute__((ext_vector_type(8))) short bf16x8;
typedef __attribute__((ext_vector_type(4))) float f32x4;

__device__ __forceinline__ float bf2f(unsigned short u) {
    union { unsigned int i; float f; } x; x.i = ((unsigned int)u) << 16; return x.f;
}
__device__ __forceinline__ unsigned short f2bf(float f) {
    union { float f; unsigned int i; } x; x.f = f;
    unsigned int r = (x.i + 0x7FFFu + ((x.i >> 16) & 1u)) >> 16;
    return (unsigned short)r;
}

// async global->LDS, 16B per lane; LDS dest = uniform base + lane*16
__device__ __forceinline__ void gload16(const void* g, void* l) {
    __builtin_amdgcn_global_load_lds(
        (const __attribute__((address_space(1))) void*)g,
        (__attribute__((address_space(3))) void*)l, 16, 0, 0);
}

// ---------------------------------------------------------------------------
// Shared GEMM core: C[64 rows][256] = post(A[.][Kpad] @ BT[256][Kpad]^T)
// 4 waves, BK=64, double-buffered gload_lds staging, XOR-swizzled LDS
// (linear LDS dest + pre-swizzled global source + swizzled ds_read).
// ---------------------------------------------------------------------------
template<int FLAGS, bool CBF>
__device__ __forceinline__
void gemm_core(const unsigned short* __restrict__ A,
               const unsigned short* __restrict__ BT,
               const float* __restrict__ bias,
               const unsigned short* __restrict__ res,
               void* __restrict__ Cv, int row0, int Mreal, int Kpad,
               unsigned short* Asl, unsigned short* Bsl)
{
    const int t    = threadIdx.x;
    const int lane = t & 63;
    const int wv   = t >> 6;
    const int l15  = lane & 15;
    const int lk   = lane >> 4;

    f32x4 acc[4][4];
#pragma unroll
    for (int i = 0; i < 4; ++i)
#pragma unroll
        for (int j = 0; j < 4; ++j) acc[i][j] = (f32x4){0.f, 0.f, 0.f, 0.f};

    const int srow8 = lane >> 3;
    const int schk  = lane & 7;

    auto stage = [&](int buf, int k0) {
#pragma unroll
        for (int j = 0; j < 2; ++j) {
            const int ii = wv * 2 + j;
            const int r  = ii * 8 + srow8;
            const int cg = schk ^ (r & 7);
            gload16(A + (size_t)(row0 + r) * Kpad + k0 + cg * 8,
                    Asl + buf * 4096 + ii * 512);
        }
#pragma unroll
        for (int j = 0; j < 8; ++j) {
            const int ii = wv * 8 + j;
            const int r  = ii * 8 + srow8;
            const int cg = schk ^ (r & 7);
            gload16(BT + (size_t)r * Kpad + k0 + cg * 8,
                    Bsl + buf * 16384 + ii * 512);
        }
    };

    auto compute = [&](int buf) {
#pragma unroll
        for (int ks = 0; ks < 2; ++ks) {
            bf16x8 af[4], bfg[4];
#pragma unroll
            for (int mi = 0; mi < 4; ++mi) {
                const int r = mi * 16 + l15;
                const int c = ks * 4 + lk;
                af[mi] = *(const bf16x8*)((const char*)(Asl + buf * 4096)
                          + r * 128 + ((c ^ (r & 7)) << 4));
            }
#pragma unroll
            for (int ni = 0; ni < 4; ++ni) {
                const int r = wv * 64 + ni * 16 + l15;
                const int c = ks * 4 + lk;
                bfg[ni] = *(const bf16x8*)((const char*)(Bsl + buf * 16384)
                           + r * 128 + ((c ^ (r & 7)) << 4));
            }
#pragma unroll
            for (int mi = 0; mi < 4; ++mi)
#pragma unroll
                for (int ni = 0; ni < 4; ++ni)
                    acc[mi][ni] = __builtin_amdgcn_mfma_f32_16x16x32_bf16(
                        af[mi], bfg[ni], acc[mi][ni], 0, 0, 0);
        }
    };

    const int nt = Kpad >> 6;
    stage(0, 0);
    __syncthreads();
    for (int tt = 0; tt < nt; ++tt) {
        const int cur = tt & 1;
        if (tt + 1 < nt) stage(cur ^ 1, (tt + 1) << 6);
        compute(cur);
        __syncthreads();
    }

#pragma unroll
    for (int mi = 0; mi < 4; ++mi) {
#pragma unroll
        for (int r = 0; r < 4; ++r) {
            const int row = row0 + mi * 16 + lk * 4 + r;
            if (row >= Mreal) continue;
#pragma unroll
            for (int ni = 0; ni < 4; ++ni) {
                const int col = wv * 64 + ni * 16 + l15;
                float o = acc[mi][ni][r];
                if (FLAGS & 2) o += bias[col];
                if (FLAGS & 1) o = fmaxf(o, 0.f);
                if (FLAGS & 4) o += bf2f(res[(size_t)row * HID + col]);
                if (CBF) ((unsigned short*)Cv)[(size_t)row * HID + col] = f2bf(o);
                else     ((float*)Cv)[(size_t)row * HID + col] = o;
            }
        }
    }
}

template<int FLAGS, bool CBF>
__global__ __launch_bounds__(256)
void mfma_gemm(const unsigned short* __restrict__ A,
               const unsigned short* __restrict__ BT,
               const float* __restrict__ bias,
               const unsigned short* __restrict__ res,
               void* __restrict__ Cv, int Mreal, int Kpad)
{
    __shared__ alignas(16) unsigned short Asl[2 * 64 * 64];
    __shared__ alignas(16) unsigned short Bsl[2 * 256 * 64];
    gemm_core<FLAGS, CBF>(A, BT, bias, res, Cv, blockIdx.x * 64, Mreal, Kpad,
                          Asl, Bsl);
}

// QKV grouped: y = bid % 3 -> consecutive blocks share the A tile (L2 reuse)
__global__ __launch_bounds__(256)
void mfma_gemm_qkv(const unsigned short* __restrict__ A,
                   const unsigned short* __restrict__ BTq,
                   const unsigned short* __restrict__ BTk,
                   const unsigned short* __restrict__ BTv,
                   unsigned short* __restrict__ Cq,
                   unsigned short* __restrict__ Ck,
                   unsigned short* __restrict__ Cvp)
{
    __shared__ alignas(16) unsigned short Asl[2 * 64 * 64];
    __shared__ alignas(16) unsigned short Bsl[2 * 256 * 64];
    const int y  = blockIdx.x % 3;
    const int xt = blockIdx.x / 3;
    const unsigned short* BT = (y == 0) ? BTq : (y == 1) ? BTk : BTv;
    unsigned short*       C  = (y == 0) ? Cq  : (y == 1) ? Ck  : Cvp;
    gemm_core<0, true>(A, BT, nullptr, nullptr, C, xt * 64, NE, 256, Asl, Bsl);
}

// ---------------------------------------------------------------------------
// Fused MLP: feats = res + relu(relu(A@L1+b1)@L2+b2), rows [r0, r0+128).
// 512 thr / 8 waves. Full A tile (128x256) resident in 4 K-tile LDS bufs;
// h written back into the A bufs between the two GEMMs (swizzled b16 stores).
// LDS 128 KB -> 1 block/CU, 2 waves/SIMD.
// ---------------------------------------------------------------------------
__global__ __launch_bounds__(512)
void mlp_fused(const unsigned short* __restrict__ A,
               const unsigned short* __restrict__ BT1,
               const float* __restrict__ b1,
               const unsigned short* __restrict__ BT2,
               const float* __restrict__ b2,
               const unsigned short* __restrict__ res,
               unsigned short* __restrict__ C)
{
    __shared__ alignas(16) unsigned short Ab[4][128 * 64];   // 4 x 16 KB
    __shared__ alignas(16) unsigned short Bb[2][256 * 64];   // 2 x 32 KB

    const int t    = threadIdx.x;
    const int lane = t & 63;
    const int wid  = t >> 6;          // 0..7
    const int wr   = wid >> 2;        // row half
    const int wc   = wid & 3;         // col quarter
    const int row0 = blockIdx.x * 128;
    const int l15  = lane & 15;
    const int lk   = lane >> 4;
    const int sub  = lane >> 3;
    const int schk = lane & 7;

    auto stageA = [&](int kt) {
#pragma unroll
        for (int j = 0; j < 2; ++j) {
            const int ii = wid * 2 + j;
            const int r  = ii * 8 + sub;                 // 0..127
            const int cg = schk ^ (r & 7);
            gload16(A + (size_t)(row0 + r) * 256 + kt * 64 + cg * 8,
                    &Ab[kt][ii * 512]);
        }
    };
    auto stageB = [&](const unsigned short* BT, int buf, int kt) {
#pragma unroll
        for (int j = 0; j < 4; ++j) {
            const int ii = wid * 4 + j;
            const int r  = ii * 8 + sub;                 // N row 0..255
            const int cg = schk ^ (r & 7);
            gload16(BT + (size_t)r * 256 + kt * 64 + cg * 8,
                    &Bb[buf][ii * 512]);
        }
    };

    f32x4 acc[4][4];
    auto zero_acc = [&]() {
#pragma unroll
        for (int i = 0; i < 4; ++i)
#pragma unroll
            for (int j = 0; j < 4; ++j) acc[i][j] = (f32x4){0.f, 0.f, 0.f, 0.f};
    };
    auto compute = [&](int kt, int buf) {
#pragma unroll
        for (int ks = 0; ks < 2; ++ks) {
            bf16x8 af[4], bfg[4];
#pragma unroll
            for (int mi = 0; mi < 4; ++mi) {
                const int r = wr * 64 + mi * 16 + l15;
                const int c = ks * 4 + lk;
                af[mi] = *(const bf16x8*)((const char*)&Ab[kt][0]
                          + r * 128 + ((c ^ (r & 7)) << 4));
            }
#pragma unroll
            for (int ni = 0; ni < 4; ++ni) {
                const int r = wc * 64 + ni * 16 + l15;
                const int c = ks * 4 + lk;
                bfg[ni] = *(const bf16x8*)((const char*)&Bb[buf][0]
                           + r * 128 + ((c ^ (r & 7)) << 4));
            }
#pragma unroll
            for (int mi = 0; mi < 4; ++mi)
#pragma unroll
                for (int ni = 0; ni < 4; ++ni)
                    acc[mi][ni] = __builtin_amdgcn_mfma_f32_16x16x32_bf16(
                        af[mi], bfg[ni], acc[mi][ni], 0, 0, 0);
        }
    };

    // ---- GEMM1: h = relu(A @ L1 + b1) ----
    zero_acc();
    stageA(0); stageA(1); stageA(2); stageA(3);
    stageB(BT1, 0, 0);
    __syncthreads();
    for (int kt = 0; kt < 4; ++kt) {
        if (kt < 3) stageB(BT1, (kt + 1) & 1, kt + 1);
        compute(kt, kt & 1);
        __syncthreads();
    }

    // write h (bias+relu, bf16) back into Ab; stage first L2 B-tile alongside
    stageB(BT2, 0, 0);
#pragma unroll
    for (int mi = 0; mi < 4; ++mi) {
#pragma unroll
        for (int r = 0; r < 4; ++r) {
            const int row = wr * 64 + mi * 16 + lk * 4 + r;    // local 0..127
#pragma unroll
            for (int ni = 0; ni < 4; ++ni) {
                const int col = wc * 64 + ni * 16 + l15;       // 0..255
                float o = acc[mi][ni][r] + b1[col];
                o = fmaxf(o, 0.f);
                const int lc = col & 63;
                const int chunk = lc >> 3;
                *(unsigned short*)((char*)&Ab[wc][0] + row * 128
                    + ((chunk ^ (row & 7)) << 4) + (lc & 7) * 2) = f2bf(o);
            }
        }
    }
    __syncthreads();

    // ---- GEMM2: C = res + relu(h @ L2 + b2) ----
    zero_acc();
    for (int kt = 0; kt < 4; ++kt) {
        if (kt < 3) stageB(BT2, (kt + 1) & 1, kt + 1);
        compute(kt, kt & 1);
        __syncthreads();
    }
#pragma unroll
    for (int mi = 0; mi < 4; ++mi) {
#pragma unroll
        for (int r = 0; r < 4; ++r) {
            const int row = row0 + wr * 64 + mi * 16 + lk * 4 + r;
            if (row >= NE) continue;
#pragma unroll
            for (int ni = 0; ni < 4; ++ni) {
                const int col = wc * 64 + ni * 16 + l15;
                float o = acc[mi][ni][r] + b2[col];
                o = fmaxf(o, 0.f);
                o += bf2f(res[(size_t)row * HID + col]);
                C[(size_t)row * HID + col] = f2bf(o);
            }
        }
    }
}

// ---------------------------------------------------------------------------
__global__ __launch_bounds__(256)
void wconv(const float* __restrict__ W, unsigned short* __restrict__ BT,
           int Kreal, int Kpad)
{
    const int idx = blockIdx.x * 256 + threadIdx.x;
    const int n = idx / Kpad, kp = idx - n * Kpad;
    float v = (kp < Kreal) ? W[(size_t)kp * HID + n] : 0.f;
    BT[idx] = f2bf(v);
}

__global__ __launch_bounds__(256)
void wconv10(const float* __restrict__ Wq, const float* __restrict__ Wk,
             const float* __restrict__ Wv, const float* __restrict__ L1w,
             const float* __restrict__ L2w, unsigned short* __restrict__ outbase)
{
    const int y = blockIdx.y;
    const int l = y / 5, which = y - l * 5;
    const float* src;
    switch (which) {
        case 0: src = Wq;  break;
        case 1: src = Wk;  break;
        case 2: src = Wv;  break;
        case 3: src = L1w; break;
        default: src = L2w; break;
    }
    src += (size_t)l * 65536;
    const int idx = blockIdx.x * 256 + threadIdx.x;
    const int n = idx >> 8, kp = idx & 255;
    outbase[(size_t)y * 65536 + idx] = f2bf(src[(size_t)kp * HID + n]);
}

// ---------------------------------------------------------------------------
__global__ __launch_bounds__(256)
void build_initA(const float* __restrict__ atom, const float* __restrict__ edge,
                 const int* __restrict__ src, unsigned short* __restrict__ out)
{
    const long total = (long)NE * 192;
    long idx = (long)blockIdx.x * blockDim.x + threadIdx.x;
    if (idx >= total) return;
    const int e = (int)(idx / 192);
    const int c = (int)(idx - (long)e * 192);
    float v = 0.f;
    if (c < 133)      v = atom[(size_t)src[e] * 133 + c];
    else if (c < 147) v = edge[(size_t)e * 14 + (c - 133)];
    out[idx] = f2bf(v);
}

__global__ __launch_bounds__(256)
void build_finalA(const float* __restrict__ atom, const float* __restrict__ fsum,
                  unsigned short* __restrict__ out)
{
    const long total = (long)NNP * 448;
    long idx = (long)blockIdx.x * blockDim.x + threadIdx.x;
    if (idx >= total) return;
    const int n = (int)(idx / 448);
    const int c = (int)(idx - (long)n * 448);
    float v = 0.f;
    if (n < NN) {
        if (c < 133)      v = atom[(size_t)n * 133 + c];
        else if (c < 389) v = fsum[(size_t)n * 256 + (c - 133)];
    }
    out[idx] = f2bf(v);
}

// ---------------------------------------------------------------------------
// CSR build
// ---------------------------------------------------------------------------
__global__ __launch_bounds__(256)
void count_keys(const int* __restrict__ key, int n, int nkeys, int* __restrict__ cnt)
{
    const int i = blockIdx.x * 256 + threadIdx.x;
    if (i < n) {
        const int kk = key[i];
        if ((unsigned)kk < (unsigned)nkeys) atomicAdd(&cnt[kk], 1);
    }
}

__global__ __launch_bounds__(256)
void fill_lists(const int* __restrict__ key, int n, int nkeys, int cap,
                int* __restrict__ cur, int* __restrict__ list)
{
    const int i = blockIdx.x * 256 + threadIdx.x;
    if (i < n) {
        const int kk = key[i];
        if ((unsigned)kk >= (unsigned)nkeys) return;
        const int pos = atomicAdd(&cur[kk], 1);
        if ((unsigned)pos < (unsigned)cap) list[pos] = i;
    }
}

__global__ __launch_bounds__(256)
void scan1(const int* __restrict__ in, int n, int* __restrict__ excl,
           int* __restrict__ part)
{
    __shared__ int sh[256];
    const int t = threadIdx.x;
    const int base = blockIdx.x * 1024 + t * 4;
    int v[4]; int s = 0;
#pragma unroll
    for (int j = 0; j < 4; ++j) { v[j] = (base + j < n) ? in[base + j] : 0; s += v[j]; }
    sh[t] = s; __syncthreads();
    for (int off = 1; off < 256; off <<= 1) {
        int x = (t >= off) ? sh[t - off] : 0;
        __syncthreads();
        sh[t] += x;
        __syncthreads();
    }
    int ex = sh[t] - s;
#pragma unroll
    for (int j = 0; j < 4; ++j) { if (base + j < n) excl[base + j] = ex; ex += v[j]; }
    if (t == 255) part[blockIdx.x] = sh[255];
}

__global__ __launch_bounds__(256)
void scan2(int* __restrict__ part, int nparts)
{
    __shared__ int sh[256];
    const int t = threadIdx.x;
    const int v = (t < nparts) ? part[t] : 0;
    sh[t] = v; __syncthreads();
    for (int off = 1; off < 256; off <<= 1) {
        int x = (t >= off) ? sh[t - off] : 0;
        __syncthreads();
        sh[t] += x;
        __syncthreads();
    }
    if (t < nparts) part[t] = sh[t] - v;
}

// offs[i] = cur[i] = excl[i] + part[i/1024]; offs[n] = total.
// counts/cur intentionally NOT restrict (they alias); read c before write.
__global__ __launch_bounds__(256)
void scan3(const int* __restrict__ excl, const int* __restrict__ part,
           const int* counts, int n, int* __restrict__ offs, int* cur)
{
    const int i = blockIdx.x * 256 + threadIdx.x;
    if (i >= n) return;
    const int v = excl[i] + part[i >> 10];
    const int c = counts[i];
    offs[i] = v;
    cur[i] = v;
    if (i == n - 1) offs[n] = v + c;
}

// ---------------------------------------------------------------------------
// Fused attention gather: 32 lanes per edge (2 edges/wave), bf16x8 loads.
// ---------------------------------------------------------------------------
__global__ __launch_bounds__(256)
void gather_v(const unsigned short* __restrict__ q, const unsigned short* __restrict__ k,
              const unsigned short* __restrict__ v,
              const int* __restrict__ toff, const int* __restrict__ tlist,
              const int* __restrict__ idx_kj,
              unsigned short* __restrict__ vc)
{
    const long gtid = (long)blockIdx.x * blockDim.x + threadIdx.x;
    const int w    = (int)(gtid >> 5);
    const int lane = threadIdx.x & 31;
    if (w >= NE) return;
    int beg = toff[w], end = toff[w + 1];
    if (beg < 0) beg = 0;
    if (end > NT) end = NT;

    const bf16x8 kv = *(const bf16x8*)(k + (size_t)w * HID + lane * 8);
    float kf[8];
#pragma unroll
    for (int j = 0; j < 8; ++j) kf[j] = bf2f((unsigned short)kv[j]);

    float av[8];
#pragma unroll
    for (int j = 0; j < 8; ++j) av[j] = 0.f;
    float den = 0.f;

    int kj_next = -1;
    if (beg < end) {
        const int tt = tlist[beg];
        kj_next = ((unsigned)tt < (unsigned)NT) ? idx_kj[tt] : -1;
    }
    for (int p = beg; p < end; ++p) {
        const int kj = kj_next;
        if (p + 1 < end) {
            const int tt = tlist[p + 1];
            kj_next = ((unsigned)tt < (unsigned)NT) ? idx_kj[tt] : -1;
        }
        if ((unsigned)kj >= (unsigned)NE) continue;
        const bf16x8 qv = *(const bf16x8*)(q + (size_t)kj * HID + lane * 8);
        float s = 0.f;
#pragma unroll
        for (int j = 0; j < 8; ++j) s += bf2f((unsigned short)qv[j]) * kf[j];
        s += __shfl_xor(s, 1);
        s += __shfl_xor(s, 2);
        const float lr = (s > 0.f) ? s : 0.2f * s;
        const float a  = __expf(lr);
        den += a;
        const bf16x8 vv = *(const bf16x8*)(v + (size_t)kj * HID + lane * 8);
#pragma unroll
        for (int j = 0; j < 8; ++j) av[j] += a * bf2f((unsigned short)vv[j]);
    }
    const float inv = (den != 0.f) ? 1.f / den : 0.f;
    bf16x8 o;
#pragma unroll
    for (int j = 0; j < 8; ++j) o[j] = (short)f2bf(av[j] * inv);
    *(bf16x8*)(vc + (size_t)w * HID + lane * 8) = o;
}

// ---------------------------------------------------------------------------
__global__ __launch_bounds__(256)
void gather_node(const unsigned short* __restrict__ feats,
                 const int* __restrict__ noff, const int* __restrict__ nlist,
                 float* __restrict__ fsum)
{
    const int w    = (int)(((long)blockIdx.x * blockDim.x + threadIdx.x) >> 6);
    const int lane = threadIdx.x & 63;
    if (w >= NN) return;
    int beg = noff[w], end = noff[w + 1];
    if (beg < 0) beg = 0;
    if (end > NE) end = NE;
    float a0 = 0.f, a1 = 0.f, a2 = 0.f, a3 = 0.f;
    for (int p = beg; p < end; ++p) {
        const int e = nlist[p];
        if ((unsigned)e >= (unsigned)NE) continue;
        const ushort4 f = *(const ushort4*)(feats + (size_t)e * HID + lane * 4);
        a0 += bf2f(f.x); a1 += bf2f(f.y); a2 += bf2f(f.z); a3 += bf2f(f.w);
    }
    float4 o = make_float4(a0, a1, a2, a3);
    *(float4*)(fsum + (size_t)w * HID + lane * 4) = o;
}

// ---------------------------------------------------------------------------
extern "C" void kernel_launch(void* const* d_in, const int* in_sizes, int n_in,
                              void* d_out, int out_size, void* d_ws, size_t ws_size,
                              hipStream_t stream)
{
    const float* atom = (const float*)d_in[0];
    const float* edge = (const float*)d_in[1];
    const float* W_i  = (const float*)d_in[2];
    const float* Wq   = (const float*)d_in[3];
    const float* Wk   = (const float*)d_in[4];
    const float* Wv   = (const float*)d_in[5];
    const float* L1w  = (const float*)d_in[6];
    const float* L1b  = (const float*)d_in[7];
    const float* L2w  = (const float*)d_in[8];
    const float* L2b  = (const float*)d_in[9];
    const float* Wo   = (const float*)d_in[10];
    const float* bo   = (const float*)d_in[11];
    const int* src    = (const int*)d_in[12];
    const int* dst    = (const int*)d_in[13];
    const int* idx_kj = (const int*)d_in[14];
    const int* idx_ji = (const int*)d_in[15];

    const size_t RB = (size_t)NE * HID * 2;   // 102,400,000 B
    char* ws = (char*)d_ws;
    unsigned short* feats = (unsigned short*)(ws);
    unsigned short* qb    = (unsigned short*)(ws + RB);
    unsigned short* kb    = (unsigned short*)(ws + 2 * RB);
    unsigned short* vb    = (unsigned short*)d_out;     // NE*256 bf16 == d_out bytes
    unsigned short* vc    = feats;                      // v_clone overlays feats
    unsigned short* initA = qb;                         // NE*192 bf16 < RB
    float*          fsum  = (float*)(ws + RB);          // NN*256 f32 == RB
    unsigned short* finalA = kb;                        // NNP*448 bf16 < RB

    char* p = ws + 3 * RB;
    int* trip_off  = (int*)p; p += 800016;
    int* trip_cur  = (int*)p; p += 800016;
    int* trip_list = (int*)p; p += 2400000;
    int* node_off  = (int*)p; p += 400016;
    int* node_cur  = (int*)p; p += 400016;
    int* node_list = (int*)p; p += 800000;
    int* tmp_excl  = (int*)p; p += 800016;
    int* partials  = (int*)p; p += 1024;
    unsigned short* wiT = (unsigned short*)p; p += (size_t)256 * 192 * 2;
    unsigned short* wT0 = (unsigned short*)p; p += (size_t)10 * 65536 * 2;
    unsigned short* woT = (unsigned short*)p; p += (size_t)256 * 448 * 2;
    const size_t NEEDED = (size_t)(p - ws);
    if (ws_size < NEEDED) return;
    auto wT = [&](int i) { return wT0 + (size_t)i * 65536; };

    // ---- weight convert/transpose/pad (bf16) ----
    wconv<<<192, 256, 0, stream>>>(W_i, wiT, 147, 192);
    wconv10<<<dim3(256, 10), 256, 0, stream>>>(Wq, Wk, Wv, L1w, L2w, wT0);
    wconv<<<448, 256, 0, stream>>>(Wo, woT, 389, 448);

    // ---- CSR build (triplets by idx_ji; edges by dst) ----
    hipMemsetAsync(trip_cur, 0, (size_t)NE * 4, stream);
    hipMemsetAsync(node_cur, 0, (size_t)NN * 4, stream);
    count_keys<<<(NT + 255) / 256, 256, 0, stream>>>(idx_ji, NT, NE, trip_cur);
    count_keys<<<(NE + 255) / 256, 256, 0, stream>>>(dst, NE, NN, node_cur);

    scan1<<<(NE + 1023) / 1024, 256, 0, stream>>>(trip_cur, NE, tmp_excl, partials);
    scan2<<<1, 256, 0, stream>>>(partials, (NE + 1023) / 1024);
    scan3<<<(NE + 255) / 256, 256, 0, stream>>>(tmp_excl, partials, trip_cur, NE, trip_off, trip_cur);
    fill_lists<<<(NT + 255) / 256, 256, 0, stream>>>(idx_ji, NT, NE, NT, trip_cur, trip_list);

    scan1<<<(NN + 1023) / 1024, 256, 0, stream>>>(node_cur, NN, tmp_excl, partials);
    scan2<<<1, 256, 0, stream>>>(partials, (NN + 1023) / 1024);
    scan3<<<(NN + 255) / 256, 256, 0, stream>>>(tmp_excl, partials, node_cur, NN, node_off, node_cur);
    fill_lists<<<(NE + 255) / 256, 256, 0, stream>>>(dst, NE, NN, NE, node_cur, node_list);

    // ---- init: feats = relu(concat(atom[src], edge) @ W_i) ----
    {
        const long total = (long)NE * 192;
        build_initA<<<(int)((total + 255) / 256), 256, 0, stream>>>(atom, edge, src, initA);
    }
    mfma_gemm<1, true><<<NE / 64, 256, 0, stream>>>(initA, wiT, nullptr, nullptr, feats, NE, 192);

    // ---- 2 attention layers ----
    for (int l = 0; l < 2; ++l) {
        const float* l1b = L1b + (size_t)l * 256;
        const float* l2b = L2b + (size_t)l * 256;

        mfma_gemm_qkv<<<3 * (NE / 64), 256, 0, stream>>>(
            feats, wT(l * 5 + 0), wT(l * 5 + 1), wT(l * 5 + 2), qb, kb, vb);

        gather_v<<<(NE * 32) / 256, 256, 0, stream>>>(qb, kb, vb, trip_off, trip_list, idx_kj, vc);

        mlp_fused<<<NEP / 128, 512, 0, stream>>>(
            vc, wT(l * 5 + 3), l1b, wT(l * 5 + 4), l2b, vb, feats);
    }

    // ---- edge -> node gather, final projection ----
    gather_node<<<NN / 4, 256, 0, stream>>>(feats, node_off, node_list, fsum);
    {
        const long total = (long)NNP * 448;
        build_finalA<<<(int)((total + 255) / 256), 256, 0, stream>>>(atom, fsum, finalA);
    }
    mfma_gemm<3, false><<<NNP / 64, 256, 0, stream>>>(finalA, woT, bo, nullptr, d_out, NN, 448);
}

// Round 7
// 1375.242 us; speedup vs baseline: 6.9076x; 1.0386x over previous
//
#include <hip/hip_runtime.h>
#include <stdint.h>

#define NN 100000
#define NNP 100096          // NN padded to multiple of 128
#define NE 200000
#define NEP 200064          // NE padded to multiple of 128
#define NT 600000
#define HID 256

typedef __attribute__((ext_vector_type(8))) short bf16x8;
typedef __attribute__((ext_vector_type(4))) float f32x4;

__device__ __forceinline__ float bf2f(unsigned short u) {
    union { unsigned int i; float f; } x; x.i = ((unsigned int)u) << 16; return x.f;
}
__device__ __forceinline__ unsigned short f2bf(float f) {
    union { float f; unsigned int i; } x; x.f = f;
    unsigned int r = (x.i + 0x7FFFu + ((x.i >> 16) & 1u)) >> 16;
    return (unsigned short)r;
}

// async global->LDS, 16B per lane; LDS dest = wave-uniform base + lane*16
__device__ __forceinline__ void gload16(const void* g, void* l) {
    __builtin_amdgcn_global_load_lds(
        (const __attribute__((address_space(1))) void*)g,
        (__attribute__((address_space(3))) void*)l, 16, 0, 0);
}

// ---------------------------------------------------------------------------
// m97-style GEMM core: C[row0..+128)[col0..+128) = post(A[.][Kpad] @ BT^T)
// 4 waves (2x2), wave tile 64x64 (acc 4x4 of 16x16), BK=64,
// single 32 KB LDS buffer, 2-barrier loop, gload_lds staging with
// pre-swizzled global source + XOR-swizzled ds_read (rule 21 pair).
// FLAGS: 1 relu, 2 +bias(before relu), 4 +res bf16(after relu). CBF: C bf16.
// ---------------------------------------------------------------------------
template<int FLAGS, bool CBF>
__device__ __forceinline__
void gemm128_core(const unsigned short* __restrict__ A,
                  const unsigned short* __restrict__ BT,
                  const float* __restrict__ bias,
                  const unsigned short* __restrict__ res,
                  void* __restrict__ Cv, int row0, int col0,
                  int Mreal, int Kpad,
                  unsigned short* Asb, unsigned short* Bsb)
{
    const int t    = threadIdx.x;
    const int lane = t & 63;
    const int wv   = t >> 6;          // 0..3
    const int wr   = wv >> 1;         // wave row half
    const int wc   = wv & 1;          // wave col half
    const int l15  = lane & 15;
    const int lk   = lane >> 4;
    const int sub  = lane >> 3;       // staging sub-row 0..7
    const int schk = lane & 7;        // staging 16B chunk 0..7

    f32x4 acc[4][4];
#pragma unroll
    for (int i = 0; i < 4; ++i)
#pragma unroll
        for (int j = 0; j < 4; ++j) acc[i][j] = (f32x4){0.f, 0.f, 0.f, 0.f};

    const int nt = Kpad >> 6;
    for (int kt = 0; kt < nt; ++kt) {
        const int k0 = kt << 6;
        // stage A tile 128x64 (16 segs of 8 rows; wave wv does segs wv*4+j)
#pragma unroll
        for (int j = 0; j < 4; ++j) {
            const int ii = wv * 4 + j;
            const int r  = ii * 8 + sub;
            const int cg = schk ^ (r & 7);
            gload16(A + (size_t)(row0 + r) * Kpad + k0 + cg * 8, Asb + ii * 512);
        }
        // stage B tile 128x64 (B rows = output cols col0..col0+127)
#pragma unroll
        for (int j = 0; j < 4; ++j) {
            const int ii = wv * 4 + j;
            const int r  = ii * 8 + sub;
            const int cg = schk ^ (r & 7);
            gload16(BT + (size_t)(col0 + r) * Kpad + k0 + cg * 8, Bsb + ii * 512);
        }
        __syncthreads();     // compiler drains vmcnt before s_barrier
#pragma unroll
        for (int ks = 0; ks < 2; ++ks) {
            bf16x8 af[4], bfg[4];
#pragma unroll
            for (int mi = 0; mi < 4; ++mi) {
                const int r = wr * 64 + mi * 16 + l15;
                const int c = ks * 4 + lk;
                af[mi] = *(const bf16x8*)((const char*)Asb
                          + r * 128 + ((c ^ (r & 7)) << 4));
            }
#pragma unroll
            for (int ni = 0; ni < 4; ++ni) {
                const int r = wc * 64 + ni * 16 + l15;
                const int c = ks * 4 + lk;
                bfg[ni] = *(const bf16x8*)((const char*)Bsb
                           + r * 128 + ((c ^ (r & 7)) << 4));
            }
#pragma unroll
            for (int mi = 0; mi < 4; ++mi)
#pragma unroll
                for (int ni = 0; ni < 4; ++ni)
                    acc[mi][ni] = __builtin_amdgcn_mfma_f32_16x16x32_bf16(
                        af[mi], bfg[ni], acc[mi][ni], 0, 0, 0);
        }
        __syncthreads();     // reads done before next stage overwrites
    }

    // epilogue: D col=l&15, row=(l>>4)*4+reg  [m89-verified]
#pragma unroll
    for (int mi = 0; mi < 4; ++mi) {
#pragma unroll
        for (int r = 0; r < 4; ++r) {
            const int row = row0 + wr * 64 + mi * 16 + lk * 4 + r;
            if (row >= Mreal) continue;
#pragma unroll
            for (int ni = 0; ni < 4; ++ni) {
                const int col = col0 + wc * 64 + ni * 16 + l15;
                float o = acc[mi][ni][r];
                if (FLAGS & 2) o += bias[col];
                if (FLAGS & 1) o = fmaxf(o, 0.f);
                if (FLAGS & 4) o += bf2f(res[(size_t)row * HID + col]);
                if (CBF) ((unsigned short*)Cv)[(size_t)row * HID + col] = f2bf(o);
                else     ((float*)Cv)[(size_t)row * HID + col] = o;
            }
        }
    }
}

// generic: grid.x = Mtiles*2; consecutive block pairs share the A tile (L2)
template<int FLAGS, bool CBF>
__global__ __launch_bounds__(256, 3)
void gemm128(const unsigned short* __restrict__ A,
             const unsigned short* __restrict__ BT,
             const float* __restrict__ bias,
             const unsigned short* __restrict__ res,
             void* __restrict__ Cv, int Mreal, int Kpad)
{
    __shared__ alignas(16) unsigned short Asb[128 * 64];
    __shared__ alignas(16) unsigned short Bsb[128 * 64];
    const int mtile = blockIdx.x >> 1;
    const int ch    = blockIdx.x & 1;
    gemm128_core<FLAGS, CBF>(A, BT, bias, res, Cv, mtile * 128, ch * 128,
                             Mreal, Kpad, Asb, Bsb);
}

// qkv: grid.x = Mtiles*6; 6 consecutive blocks (3 proj x 2 halves) share A
__global__ __launch_bounds__(256, 3)
void gemm128_qkv(const unsigned short* __restrict__ A,
                 const unsigned short* __restrict__ BTq,
                 const unsigned short* __restrict__ BTk,
                 const unsigned short* __restrict__ BTv,
                 unsigned short* __restrict__ Cq,
                 unsigned short* __restrict__ Ck,
                 unsigned short* __restrict__ Cvp)
{
    __shared__ alignas(16) unsigned short Asb[128 * 64];
    __shared__ alignas(16) unsigned short Bsb[128 * 64];
    const int mtile = blockIdx.x / 6;
    const int s     = blockIdx.x % 6;
    const int proj  = s >> 1;
    const int ch    = s & 1;
    const unsigned short* BT = (proj == 0) ? BTq : (proj == 1) ? BTk : BTv;
    unsigned short*       C  = (proj == 0) ? Cq  : (proj == 1) ? Ck  : Cvp;
    gemm128_core<0, true>(A, BT, nullptr, nullptr, C, mtile * 128, ch * 128,
                          NE, 256, Asb, Bsb);
}

// ---------------------------------------------------------------------------
__global__ __launch_bounds__(256)
void wconv(const float* __restrict__ W, unsigned short* __restrict__ BT,
           int Kreal, int Kpad)
{
    const int idx = blockIdx.x * 256 + threadIdx.x;
    const int n = idx / Kpad, kp = idx - n * Kpad;
    float v = (kp < Kreal) ? W[(size_t)kp * HID + n] : 0.f;
    BT[idx] = f2bf(v);
}

__global__ __launch_bounds__(256)
void wconv10(const float* __restrict__ Wq, const float* __restrict__ Wk,
             const float* __restrict__ Wv, const float* __restrict__ L1w,
             const float* __restrict__ L2w, unsigned short* __restrict__ outbase)
{
    const int y = blockIdx.y;
    const int l = y / 5, which = y - l * 5;
    const float* src;
    switch (which) {
        case 0: src = Wq;  break;
        case 1: src = Wk;  break;
        case 2: src = Wv;  break;
        case 3: src = L1w; break;
        default: src = L2w; break;
    }
    src += (size_t)l * 65536;
    const int idx = blockIdx.x * 256 + threadIdx.x;
    const int n = idx >> 8, kp = idx & 255;
    outbase[(size_t)y * 65536 + idx] = f2bf(src[(size_t)kp * HID + n]);
}

// ---------------------------------------------------------------------------
__global__ __launch_bounds__(256)
void build_initA(const float* __restrict__ atom, const float* __restrict__ edge,
                 const int* __restrict__ src, unsigned short* __restrict__ out)
{
    const long total = (long)NE * 192;
    long idx = (long)blockIdx.x * blockDim.x + threadIdx.x;
    if (idx >= total) return;
    const int e = (int)(idx / 192);
    const int c = (int)(idx - (long)e * 192);
    float v = 0.f;
    if (c < 133)      v = atom[(size_t)src[e] * 133 + c];
    else if (c < 147) v = edge[(size_t)e * 14 + (c - 133)];
    out[idx] = f2bf(v);
}

__global__ __launch_bounds__(256)
void build_finalA(const float* __restrict__ atom, const float* __restrict__ fsum,
                  unsigned short* __restrict__ out)
{
    const long total = (long)NNP * 448;
    long idx = (long)blockIdx.x * blockDim.x + threadIdx.x;
    if (idx >= total) return;
    const int n = (int)(idx / 448);
    const int c = (int)(idx - (long)n * 448);
    float v = 0.f;
    if (n < NN) {
        if (c < 133)      v = atom[(size_t)n * 133 + c];
        else if (c < 389) v = fsum[(size_t)n * 256 + (c - 133)];
    }
    out[idx] = f2bf(v);
}

// ---------------------------------------------------------------------------
// CSR build
// ---------------------------------------------------------------------------
__global__ __launch_bounds__(256)
void count_keys(const int* __restrict__ key, int n, int nkeys, int* __restrict__ cnt)
{
    const int i = blockIdx.x * 256 + threadIdx.x;
    if (i < n) {
        const int kk = key[i];
        if ((unsigned)kk < (unsigned)nkeys) atomicAdd(&cnt[kk], 1);
    }
}

__global__ __launch_bounds__(256)
void fill_lists(const int* __restrict__ key, int n, int nkeys, int cap,
                int* __restrict__ cur, int* __restrict__ list)
{
    const int i = blockIdx.x * 256 + threadIdx.x;
    if (i < n) {
        const int kk = key[i];
        if ((unsigned)kk >= (unsigned)nkeys) return;
        const int pos = atomicAdd(&cur[kk], 1);
        if ((unsigned)pos < (unsigned)cap) list[pos] = i;
    }
}

__global__ __launch_bounds__(256)
void scan1(const int* __restrict__ in, int n, int* __restrict__ excl,
           int* __restrict__ part)
{
    __shared__ int sh[256];
    const int t = threadIdx.x;
    const int base = blockIdx.x * 1024 + t * 4;
    int v[4]; int s = 0;
#pragma unroll
    for (int j = 0; j < 4; ++j) { v[j] = (base + j < n) ? in[base + j] : 0; s += v[j]; }
    sh[t] = s; __syncthreads();
    for (int off = 1; off < 256; off <<= 1) {
        int x = (t >= off) ? sh[t - off] : 0;
        __syncthreads();
        sh[t] += x;
        __syncthreads();
    }
    int ex = sh[t] - s;
#pragma unroll
    for (int j = 0; j < 4; ++j) { if (base + j < n) excl[base + j] = ex; ex += v[j]; }
    if (t == 255) part[blockIdx.x] = sh[255];
}

__global__ __launch_bounds__(256)
void scan2(int* __restrict__ part, int nparts)
{
    __shared__ int sh[256];
    const int t = threadIdx.x;
    const int v = (t < nparts) ? part[t] : 0;
    sh[t] = v; __syncthreads();
    for (int off = 1; off < 256; off <<= 1) {
        int x = (t >= off) ? sh[t - off] : 0;
        __syncthreads();
        sh[t] += x;
        __syncthreads();
    }
    if (t < nparts) part[t] = sh[t] - v;
}

// offs[i] = cur[i] = excl[i] + part[i/1024]; offs[n] = total.
// counts/cur intentionally NOT restrict (they alias); read c before write.
__global__ __launch_bounds__(256)
void scan3(const int* __restrict__ excl, const int* __restrict__ part,
           const int* counts, int n, int* __restrict__ offs, int* cur)
{
    const int i = blockIdx.x * 256 + threadIdx.x;
    if (i >= n) return;
    const int v = excl[i] + part[i >> 10];
    const int c = counts[i];
    offs[i] = v;
    cur[i] = v;
    if (i == n - 1) offs[n] = v + c;
}

// ---------------------------------------------------------------------------
// Fused attention gather: 32 lanes per edge (2 edges/wave), bf16x8 loads.
// ---------------------------------------------------------------------------
__global__ __launch_bounds__(256)
void gather_v(const unsigned short* __restrict__ q, const unsigned short* __restrict__ k,
              const unsigned short* __restrict__ v,
              const int* __restrict__ toff, const int* __restrict__ tlist,
              const int* __restrict__ idx_kj,
              unsigned short* __restrict__ vc)
{
    const long gtid = (long)blockIdx.x * blockDim.x + threadIdx.x;
    const int w    = (int)(gtid >> 5);
    const int lane = threadIdx.x & 31;
    if (w >= NE) return;
    int beg = toff[w], end = toff[w + 1];
    if (beg < 0) beg = 0;
    if (end > NT) end = NT;

    const bf16x8 kv = *(const bf16x8*)(k + (size_t)w * HID + lane * 8);
    float kf[8];
#pragma unroll
    for (int j = 0; j < 8; ++j) kf[j] = bf2f((unsigned short)kv[j]);

    float av[8];
#pragma unroll
    for (int j = 0; j < 8; ++j) av[j] = 0.f;
    float den = 0.f;

    int kj_next = -1;
    if (beg < end) {
        const int tt = tlist[beg];
        kj_next = ((unsigned)tt < (unsigned)NT) ? idx_kj[tt] : -1;
    }
    for (int p = beg; p < end; ++p) {
        const int kj = kj_next;
        if (p + 1 < end) {
            const int tt = tlist[p + 1];
            kj_next = ((unsigned)tt < (unsigned)NT) ? idx_kj[tt] : -1;
        }
        if ((unsigned)kj >= (unsigned)NE) continue;
        const bf16x8 qv = *(const bf16x8*)(q + (size_t)kj * HID + lane * 8);
        float s = 0.f;
#pragma unroll
        for (int j = 0; j < 8; ++j) s += bf2f((unsigned short)qv[j]) * kf[j];
        s += __shfl_xor(s, 1);
        s += __shfl_xor(s, 2);
        const float lr = (s > 0.f) ? s : 0.2f * s;
        const float a  = __expf(lr);
        den += a;
        const bf16x8 vv = *(const bf16x8*)(v + (size_t)kj * HID + lane * 8);
#pragma unroll
        for (int j = 0; j < 8; ++j) av[j] += a * bf2f((unsigned short)vv[j]);
    }
    const float inv = (den != 0.f) ? 1.f / den : 0.f;
    bf16x8 o;
#pragma unroll
    for (int j = 0; j < 8; ++j) o[j] = (short)f2bf(av[j] * inv);
    *(bf16x8*)(vc + (size_t)w * HID + lane * 8) = o;
}

// ---------------------------------------------------------------------------
__global__ __launch_bounds__(256)
void gather_node(const unsigned short* __restrict__ feats,
                 const int* __restrict__ noff, const int* __restrict__ nlist,
                 float* __restrict__ fsum)
{
    const int w    = (int)(((long)blockIdx.x * blockDim.x + threadIdx.x) >> 6);
    const int lane = threadIdx.x & 63;
    if (w >= NN) return;
    int beg = noff[w], end = noff[w + 1];
    if (beg < 0) beg = 0;
    if (end > NE) end = NE;
    float a0 = 0.f, a1 = 0.f, a2 = 0.f, a3 = 0.f;
    for (int p = beg; p < end; ++p) {
        const int e = nlist[p];
        if ((unsigned)e >= (unsigned)NE) continue;
        const ushort4 f = *(const ushort4*)(feats + (size_t)e * HID + lane * 4);
        a0 += bf2f(f.x); a1 += bf2f(f.y); a2 += bf2f(f.z); a3 += bf2f(f.w);
    }
    float4 o = make_float4(a0, a1, a2, a3);
    *(float4*)(fsum + (size_t)w * HID + lane * 4) = o;
}

// ---------------------------------------------------------------------------
extern "C" void kernel_launch(void* const* d_in, const int* in_sizes, int n_in,
                              void* d_out, int out_size, void* d_ws, size_t ws_size,
                              hipStream_t stream)
{
    const float* atom = (const float*)d_in[0];
    const float* edge = (const float*)d_in[1];
    const float* W_i  = (const float*)d_in[2];
    const float* Wq   = (const float*)d_in[3];
    const float* Wk   = (const float*)d_in[4];
    const float* Wv   = (const float*)d_in[5];
    const float* L1w  = (const float*)d_in[6];
    const float* L1b  = (const float*)d_in[7];
    const float* L2w  = (const float*)d_in[8];
    const float* L2b  = (const float*)d_in[9];
    const float* Wo   = (const float*)d_in[10];
    const float* bo   = (const float*)d_in[11];
    const int* src    = (const int*)d_in[12];
    const int* dst    = (const int*)d_in[13];
    const int* idx_kj = (const int*)d_in[14];
    const int* idx_ji = (const int*)d_in[15];

    const size_t RB = (size_t)NE * HID * 2;   // 102,400,000 B
    char* ws = (char*)d_ws;
    unsigned short* feats = (unsigned short*)(ws);
    unsigned short* qb    = (unsigned short*)(ws + RB);
    unsigned short* kb    = (unsigned short*)(ws + 2 * RB);
    unsigned short* vb    = (unsigned short*)d_out;     // NE*256 bf16 == d_out bytes
    unsigned short* vc    = feats;                      // v_clone overlays feats
    unsigned short* initA = qb;                         // NEP*192 bf16 = 76.8MB < RB
    unsigned short* h1    = kb;
    float*          fsum  = (float*)(ws + RB);          // NN*256 f32 == RB
    unsigned short* finalA = kb;                        // NNP*448 bf16 = 89.7MB < RB

    char* p = ws + 3 * RB;
    int* trip_off  = (int*)p; p += 800016;
    int* trip_cur  = (int*)p; p += 800016;
    int* trip_list = (int*)p; p += 2400000;
    int* node_off  = (int*)p; p += 400016;
    int* node_cur  = (int*)p; p += 400016;
    int* node_list = (int*)p; p += 800000;
    int* tmp_excl  = (int*)p; p += 800016;
    int* partials  = (int*)p; p += 1024;
    unsigned short* wiT = (unsigned short*)p; p += (size_t)256 * 192 * 2;
    unsigned short* wT0 = (unsigned short*)p; p += (size_t)10 * 65536 * 2;
    unsigned short* woT = (unsigned short*)p; p += (size_t)256 * 448 * 2;
    const size_t NEEDED = (size_t)(p - ws);
    if (ws_size < NEEDED) return;
    auto wT = [&](int i) { return wT0 + (size_t)i * 65536; };

    // ---- weight convert/transpose/pad (bf16) ----
    wconv<<<192, 256, 0, stream>>>(W_i, wiT, 147, 192);
    wconv10<<<dim3(256, 10), 256, 0, stream>>>(Wq, Wk, Wv, L1w, L2w, wT0);
    wconv<<<448, 256, 0, stream>>>(Wo, woT, 389, 448);

    // ---- CSR build (triplets by idx_ji; edges by dst) ----
    hipMemsetAsync(trip_cur, 0, (size_t)NE * 4, stream);
    hipMemsetAsync(node_cur, 0, (size_t)NN * 4, stream);
    count_keys<<<(NT + 255) / 256, 256, 0, stream>>>(idx_ji, NT, NE, trip_cur);
    count_keys<<<(NE + 255) / 256, 256, 0, stream>>>(dst, NE, NN, node_cur);

    scan1<<<(NE + 1023) / 1024, 256, 0, stream>>>(trip_cur, NE, tmp_excl, partials);
    scan2<<<1, 256, 0, stream>>>(partials, (NE + 1023) / 1024);
    scan3<<<(NE + 255) / 256, 256, 0, stream>>>(tmp_excl, partials, trip_cur, NE, trip_off, trip_cur);
    fill_lists<<<(NT + 255) / 256, 256, 0, stream>>>(idx_ji, NT, NE, NT, trip_cur, trip_list);

    scan1<<<(NN + 1023) / 1024, 256, 0, stream>>>(node_cur, NN, tmp_excl, partials);
    scan2<<<1, 256, 0, stream>>>(partials, (NN + 1023) / 1024);
    scan3<<<(NN + 255) / 256, 256, 0, stream>>>(tmp_excl, partials, node_cur, NN, node_off, node_cur);
    fill_lists<<<(NE + 255) / 256, 256, 0, stream>>>(dst, NE, NN, NE, node_cur, node_list);

    // ---- init: feats = relu(concat(atom[src], edge) @ W_i) ----
    {
        const long total = (long)NE * 192;
        build_initA<<<(int)((total + 255) / 256), 256, 0, stream>>>(atom, edge, src, initA);
    }
    gemm128<1, true><<<(NEP / 128) * 2, 256, 0, stream>>>(initA, wiT, nullptr, nullptr,
                                                          feats, NE, 192);

    // ---- 2 attention layers ----
    for (int l = 0; l < 2; ++l) {
        const float* l1b = L1b + (size_t)l * 256;
        const float* l2b = L2b + (size_t)l * 256;

        gemm128_qkv<<<(NEP / 128) * 6, 256, 0, stream>>>(
            feats, wT(l * 5 + 0), wT(l * 5 + 1), wT(l * 5 + 2), qb, kb, vb);

        gather_v<<<(NE * 32) / 256, 256, 0, stream>>>(qb, kb, vb, trip_off, trip_list, idx_kj, vc);

        // h1 = relu(vc @ L1 + b1); feats = v + relu(h1 @ L2 + b2)
        gemm128<3, true><<<(NEP / 128) * 2, 256, 0, stream>>>(vc, wT(l * 5 + 3), l1b,
                                                              nullptr, h1, NE, 256);
        gemm128<7, true><<<(NEP / 128) * 2, 256, 0, stream>>>(h1, wT(l * 5 + 4), l2b,
                                                              vb, feats, NE, 256);
    }

    // ---- edge -> node gather, final projection ----
    gather_node<<<NN / 4, 256, 0, stream>>>(feats, node_off, node_list, fsum);
    {
        const long total = (long)NNP * 448;
        build_finalA<<<(int)((total + 255) / 256), 256, 0, stream>>>(atom, fsum, finalA);
    }
    gemm128<3, false><<<(NNP / 128) * 2, 256, 0, stream>>>(finalA, woT, bo, nullptr,
                                                           d_out, NN, 448);
}